// Round 17
// baseline (162.852 us; speedup 1.0000x reference)
//
#include <hip/hip_runtime.h>
#include <hip/hip_fp16.h>
#include <cmath>
#include <cstdint>

#define NB 8
#define NL 16
#define TD 8192
#define NPIX 65536
#define CH 32
#define SD 512

static constexpr uint32_t PRIME = 2654435761u;

typedef __attribute__((ext_vector_type(8))) short bf16x8;
typedef __attribute__((ext_vector_type(4))) float f32x4;

// per-level corner-tile capacities for a 16x16 tile (+halo, 17-px span)
static constexpr int cNCX[16] = {4,5,5,5,6,6,7,7,8,9,10,12,13,15,18,20};
static constexpr int CTOFF[17] = {0,16,41,66,91,127,163,212,261,325,406,506,650,819,1044,1368,1768};

struct LevelParams {
    int res[NL];
    int hashed[NL];
    int uoff[NL];    // prefix of 256*r u32 (per batch) into packed U [i][cx]
    int soff[NL];    // prefix of (r+2) ints into stab
    int cwoff[NL];   // recon2 wave prefix (r*nck)
    int nck[NL];     // ceil(r/64)
    int sumr;
    int nwaves;      // recon2 waves per batch
};

// ---- bf16 helpers (RNE) ----
__device__ __forceinline__ unsigned short f2bf(float f) {
    uint32_t u = __float_as_uint(f);
    return (unsigned short)((u + 0x7fffu + ((u >> 16) & 1u)) >> 16);
}
__device__ __forceinline__ float bflo(uint32_t u) { return __uint_as_float(u << 16); }
__device__ __forceinline__ float bfhi(uint32_t u) { return __uint_as_float(u & 0xffff0000u); }
__device__ __forceinline__ uint32_t packbf(float a, float b) {
    return (uint32_t)f2bf(a) | ((uint32_t)f2bf(b) << 16);
}
// ---- fp16x2 pack helpers for U ----
__device__ __forceinline__ uint32_t packh2(float a, float b) {
    return (uint32_t)__half_as_ushort(__float2half_rn(a)) |
           ((uint32_t)__half_as_ushort(__float2half_rn(b)) << 16);
}
__device__ __forceinline__ float h2lo(uint32_t u) {
    return __half2float(__ushort_as_half((unsigned short)(u & 0xffffu)));
}
__device__ __forceinline__ float h2hi(uint32_t u) {
    return __half2float(__ushort_as_half((unsigned short)(u >> 16)));
}

// ---- K_prep: styles+dcoef (blocks 0..7), wtab (8..23), wpack (24..59) ----
__global__ __launch_bounds__(256) void k_prep(
    const float* __restrict__ s, const float* __restrict__ aw,
    const float* __restrict__ ab, const float* __restrict__ cw,
    const float* __restrict__ coords,
    float* __restrict__ styles, float* __restrict__ dcoef,
    int* __restrict__ ctab, float* __restrict__ ftab, int* __restrict__ stab,
    unsigned short* __restrict__ wpack, LevelParams p) {
    int bb = blockIdx.x;
    int t = threadIdx.x;
    if (bb < NB) {
        int b = bb;
        int c = t >> 3, part = t & 7;               // 32 ch x 8 parts
        const float* sv = s + b * SD + part * 64;
        const float* wv = aw + c * SD + part * 64;
        float acc = 0.f;
        #pragma unroll 8
        for (int k = 0; k < 64; ++k) acc += sv[k] * wv[k];
        acc += __shfl_xor(acc, 1, 64);
        acc += __shfl_xor(acc, 2, 64);
        acc += __shfl_xor(acc, 4, 64);
        __shared__ float st_sh[CH];
        if (part == 0) {
            float st = acc * 0.04419417382415922f /* 1/sqrt(512) */ + ab[c];
            styles[b * CH + c] = st;
            st_sh[c] = st;
        }
        __syncthreads();
        if (t < CH) {
            float d = 0.f;
            for (int i = 0; i < CH; ++i) {
                const float* w9 = cw + (t * CH + i) * 9;
                float ws = 0.f;
                #pragma unroll
                for (int k = 0; k < 9; ++k) ws += w9[k] * w9[k];
                float si = st_sh[i];
                d += ws * si * si;
            }
            dcoef[b * CH + t] = rsqrtf(d + 1e-8f);
        }
    } else if (bb < NB + NL) {
        int l = bb - NB;
        int j = t;
        int r = p.res[l];
        float g = coords[2 * j];                   // x-coord of col j == y-coord of row j
        float px = g * (float)(r - 1);
        float fl = floorf(px);
        float f = px - fl;
        int c = min((int)fl, r - 2);
        ctab[l * 256 + j] = c;
        ftab[l * 256 + j] = f;
        __shared__ int cs[256];
        cs[j] = c;
        __syncthreads();
        for (int cc = j; cc <= r; cc += 256) {
            int cnt = 0;
            for (int i = 0; i < 256; ++i) cnt += (cs[i] < cc) ? 1 : 0;
            stab[p.soff[l] + cc] = cnt;
        }
    } else {
        int idx = (bb - NB - NL) * 256 + t;
        if (idx < 9 * 4 * 32 * 8) {
            int j = idx & 7;
            int o = (idx >> 3) & 31;
            int kgi = (idx >> 8) & 3;
            int tap = idx >> 10;
            wpack[idx] = f2bf(cw[(o * 32 + kgi * 8 + j) * 9 + tap]);
        }
    }
}

// ---- fused retrieve feature from (cell-rel,frac) + LDS corners ----
template<int L>
__device__ __forceinline__ uint32_t feat1p(float2 cv, float2 rv, const uint32_t* ctile) {
    int a = CTOFF[L] + __float_as_int(rv.x) * cNCX[L] + __float_as_int(cv.x);
    float fx = cv.y, fy = rv.y;
    uint32_t c00 = ctile[a], c10 = ctile[a + 1];             // ds_read2_b32
    uint32_t c01 = ctile[a + cNCX[L]], c11 = ctile[a + cNCX[L] + 1];
    float w00 = (1.f - fx) * (1.f - fy), w10 = fx * (1.f - fy);
    float w01 = (1.f - fx) * fy,         w11 = fx * fy;
    float f0 = w00 * bflo(c00) + w10 * bflo(c10) + w01 * bflo(c01) + w11 * bflo(c11);
    float f1 = w00 * bfhi(c00) + w10 * bfhi(c10) + w01 * bfhi(c01) + w11 * bfhi(c11);
    return packbf(f0, f1);
}

// ---- phase 1: one wave = 4 levels, all 324 halo px ----
template<int L0>
__device__ __forceinline__ void phase1(int lane, int tx0, int ty0,
                                       const float2* col2, const float2* row2,
                                       const uint32_t* ctile, uint32_t* xt) {
    constexpr int q = L0 / 4;
    #pragma unroll
    for (int it = 0; it < 6; ++it) {
        int pl = it * 64 + lane;
        int rr = pl / 18, cc = pl - rr * 18;
        int gy = ty0 + rr - 1, gx = tx0 + cc - 1;
        uint4 v = make_uint4(0u, 0u, 0u, 0u);
        if (pl < 324 && (unsigned)gy < 256u && (unsigned)gx < 256u) {
            float2 cv0 = col2[(L0 + 0) * 18 + cc], rv0 = row2[(L0 + 0) * 18 + rr];
            float2 cv1 = col2[(L0 + 1) * 18 + cc], rv1 = row2[(L0 + 1) * 18 + rr];
            float2 cv2 = col2[(L0 + 2) * 18 + cc], rv2 = row2[(L0 + 2) * 18 + rr];
            float2 cv3 = col2[(L0 + 3) * 18 + cc], rv3 = row2[(L0 + 3) * 18 + rr];
            v.x = feat1p<L0 + 0>(cv0, rv0, ctile);
            v.y = feat1p<L0 + 1>(cv1, rv1, ctile);
            v.z = feat1p<L0 + 2>(cv2, rv2, ctile);
            v.w = feat1p<L0 + 3>(cv3, rv3, ctile);
        }
        if (pl < 324)
            *(uint4*)(xt + (size_t)(pl * 4 + (q ^ (cc & 3))) * 4) = v;
    }
}

// ---- shared setup body (phases 0a, 0b-i, 0b-ii) used by real conv + ablations ----
__device__ __forceinline__ void conv_setup(
    int tid, int b, int tx0, int ty0,
    const float* __restrict__ tb, const int* __restrict__ ctab,
    const float* __restrict__ ftab, const float* __restrict__ styles,
    uint32_t* ctile, float2* col2, float2* row2,
    int* cxbase, int* cybase, int* ncxA, int* ncyA, LevelParams& p) {
    if (tid < NL) {
        int l = tid;
        int cxb = ctab[l * 256 + max(tx0 - 1, 0)];
        int cyb = ctab[l * 256 + max(ty0 - 1, 0)];
        cxbase[l] = cxb;
        cybase[l] = cyb;
        ncxA[l] = ctab[l * 256 + min(tx0 + 16, 255)] - cxb + 2;
        ncyA[l] = ctab[l * 256 + min(ty0 + 16, 255)] - cyb + 2;
    }
    __syncthreads();
    for (int u0 = tid; u0 < NL * 36; u0 += 256) {
        int l = u0 / 36, pos = u0 - l * 36;
        if (pos < 18) {
            int gx = tx0 - 1 + pos;
            int gxc = min(max(gx, 0), 255);
            col2[l * 18 + pos] = make_float2(
                __int_as_float(ctab[l * 256 + gxc] - cxbase[l]), ftab[l * 256 + gxc]);
        } else {
            int pr = pos - 18;
            int gy = ty0 - 1 + pr;
            int gyc = min(max(gy, 0), 255);
            row2[l * 18 + pr] = make_float2(
                __int_as_float(ctab[l * 256 + gyc] - cybase[l]), ftab[l * 256 + gyc]);
        }
    }
    #pragma unroll
    for (int l = 0; l < NL; ++l) {
        const int NCXl = cNCX[l];
        const int CAP = (CTOFF[l + 1] - CTOFF[l]);
        float s0 = styles[b * CH + 2 * l], s1 = styles[b * CH + 2 * l + 1];
        for (int u2 = tid; u2 < CAP; u2 += 256) {
            int sy = u2 / NCXl;
            int sx = u2 - sy * NCXl;
            if (sx < ncxA[l] && sy < ncyA[l]) {
                int ax = cxbase[l] + sx, ay = cybase[l] + sy;
                int r = p.res[l];
                uint32_t idx = p.hashed[l]
                    ? (((uint32_t)ax ^ ((uint32_t)ay * PRIME)) & (TD - 1))
                    : (uint32_t)(ay * r + ax);
                float2 g = *(const float2*)(tb + (size_t)l * TD * 2 + 2 * idx);
                ctile[CTOFF[l] + sy * NCXl + sx] = packbf(g.x * s0, g.y * s1);
            }
        }
    }
    __syncthreads();
}

// ---- ABLATION 1: setup only; keep-alive XOR write into tokens (overwritten later) ----
__global__ __launch_bounds__(256) void k_conv_ab1(
    const float* __restrict__ tables, const int* __restrict__ ctab,
    const float* __restrict__ ftab, const float* __restrict__ styles,
    uint32_t* __restrict__ tokens, LevelParams p) {
    __shared__ uint32_t ctile[1768];
    __shared__ float2 col2[NL * 18];
    __shared__ float2 row2[NL * 18];
    __shared__ int cxbase[NL], cybase[NL], ncxA[NL], ncyA[NL];
    int bid = blockIdx.x;
    int b = bid & 7;
    int t = bid >> 3;
    int tx0 = (t & 15) * 16, ty0 = (t >> 4) * 16;
    int tid = threadIdx.x;
    const float* tb = tables + (size_t)b * NL * TD * 2;
    conv_setup(tid, b, tx0, ty0, tb, ctab, ftab, styles,
               ctile, col2, row2, cxbase, cybase, ncxA, ncyA, p);
    uint32_t acc = 0u;
    for (int i = tid; i < 1768; i += 256) acc ^= ctile[i];
    acc ^= __float_as_uint(col2[tid % 288].y) ^ __float_as_uint(row2[tid % 288].y);
    tokens[(size_t)bid * 256 + tid] = acc;     // garbage; real conv overwrites all
}

// ---- ABLATION 2: setup + phase 1; keep-alive XOR of xt into tokens ----
__global__ __launch_bounds__(256) void k_conv_ab2(
    const float* __restrict__ tables, const int* __restrict__ ctab,
    const float* __restrict__ ftab, const float* __restrict__ styles,
    uint32_t* __restrict__ tokens, LevelParams p) {
    __shared__ uint32_t xt[18 * 18 * 16];
    __shared__ uint32_t ctile[1768];
    __shared__ float2 col2[NL * 18];
    __shared__ float2 row2[NL * 18];
    __shared__ int cxbase[NL], cybase[NL], ncxA[NL], ncyA[NL];
    int bid = blockIdx.x;
    int b = bid & 7;
    int t = bid >> 3;
    int tx0 = (t & 15) * 16, ty0 = (t >> 4) * 16;
    int tid = threadIdx.x;
    int lane = tid & 63, wv = tid >> 6;
    const float* tb = tables + (size_t)b * NL * TD * 2;
    conv_setup(tid, b, tx0, ty0, tb, ctab, ftab, styles,
               ctile, col2, row2, cxbase, cybase, ncxA, ncyA, p);
    switch (wv) {
        case 0: phase1<0>(lane, tx0, ty0, col2, row2, ctile, xt); break;
        case 1: phase1<4>(lane, tx0, ty0, col2, row2, ctile, xt); break;
        case 2: phase1<8>(lane, tx0, ty0, col2, row2, ctile, xt); break;
        default: phase1<12>(lane, tx0, ty0, col2, row2, ctile, xt); break;
    }
    __syncthreads();
    uint32_t acc = 0u;
    for (int i = tid; i < 5184; i += 256) acc ^= xt[i];
    tokens[(size_t)bid * 256 + tid] = acc;     // garbage; real conv overwrites all
}

// ---- K2: FUSED hash-retrieve + modulation + MFMA 3x3 conv + demod/bias/lrelu ----
__global__ __launch_bounds__(256) void k_conv(
    const float* __restrict__ tables, const int* __restrict__ ctab,
    const float* __restrict__ ftab, const float* __restrict__ styles,
    const unsigned short* __restrict__ wpack, const float* __restrict__ cb,
    const float* __restrict__ dcoef, uint32_t* __restrict__ tokens,
    LevelParams p) {
    __shared__ uint32_t xt[18 * 18 * 16];      // 20736 B feature tile (bf16x2 chunks)
    __shared__ uint32_t ctile[1768];           // 7072 B deduped premod corners (bf16x2)
    __shared__ float2 col2[NL * 18];           // 2304 B (cell-rel, frac) per halo col
    __shared__ float2 row2[NL * 18];           // 2304 B per halo row
    __shared__ int cxbase[NL], cybase[NL], ncxA[NL], ncyA[NL];

    int bid = blockIdx.x;
    int b = bid & 7;
    int t = bid >> 3;
    int tx0 = (t & 15) * 16, ty0 = (t >> 4) * 16;
    int tid = threadIdx.x;
    int lane = tid & 63, wv = tid >> 6;        // 4 waves
    int npx = lane & 15, kg = lane >> 4;
    const float* tb = tables + (size_t)b * NL * TD * 2;

    conv_setup(tid, b, tx0, ty0, tb, ctab, ftab, styles,
               ctile, col2, row2, cxbase, cybase, ncxA, ncyA, p);

    // ---- phase 1: wave-uniform 4-level feature computation -> xt (all-LDS) ----
    switch (wv) {
        case 0: phase1<0>(lane, tx0, ty0, col2, row2, ctile, xt); break;
        case 1: phase1<4>(lane, tx0, ty0, col2, row2, ctile, xt); break;
        case 2: phase1<8>(lane, tx0, ty0, col2, row2, ctile, xt); break;
        default: phase1<12>(lane, tx0, ty0, col2, row2, ctile, xt); break;
    }
    __builtin_amdgcn_sched_barrier(0);         // keep wf loads out of phase-1 live range

    // ---- weights (prepacked bf16 fragments) + demod/bias, loaded AFTER phase 1 ----
    bf16x8 wf[9][2];
    #pragma unroll
    for (int tp = 0; tp < 9; ++tp) {
        wf[tp][0] = *(const bf16x8*)(wpack + (size_t)((tp * 4 + kg) * 32 + npx) * 8);
        wf[tp][1] = *(const bf16x8*)(wpack + (size_t)((tp * 4 + kg) * 32 + 16 + npx) * 8);
    }
    float dc[2][4], bs[2][4];
    #pragma unroll
    for (int ob = 0; ob < 2; ++ob)
        #pragma unroll
        for (int rg = 0; rg < 4; ++rg) {
            int oc = ob * 16 + kg * 4 + rg;
            dc[ob][rg] = dcoef[b * CH + oc];
            bs[ob][rg] = cb[oc];
        }
    __syncthreads();

    // ---- phase 2: MFMA conv (4 iterations per wave; group = one 16-px row) ----
    #pragma unroll 1
    for (int it = 0; it < 4; ++it) {
        int py_l = it * 4 + wv;                // 16 rows
        int px_l = npx;
        f32x4 a0 = {0.f, 0.f, 0.f, 0.f};
        f32x4 a1 = {0.f, 0.f, 0.f, 0.f};
        #pragma unroll
        for (int ky = 0; ky < 3; ++ky) {
            int rowb = (py_l + ky) * 18;
            #pragma unroll
            for (int kx = 0; kx < 3; ++kx) {
                int cc = px_l + kx;
                bf16x8 bf = *(const bf16x8*)(xt + (((rowb + cc) << 2) + (kg ^ (cc & 3))) * 4);
                a0 = __builtin_amdgcn_mfma_f32_16x16x32_bf16(wf[ky * 3 + kx][0], bf, a0, 0, 0, 0);
                a1 = __builtin_amdgcn_mfma_f32_16x16x32_bf16(wf[ky * 3 + kx][1], bf, a1, 0, 0, 0);
            }
        }
        int py = ty0 + py_l, px = tx0 + px_l;
        size_t pbase = (size_t)py * 256 + px;
        {
            float y0 = a0[0] * dc[0][0] + bs[0][0];
            float y1 = a0[1] * dc[0][1] + bs[0][1];
            float y2 = a0[2] * dc[0][2] + bs[0][2];
            float y3 = a0[3] * dc[0][3] + bs[0][3];
            y0 = (y0 > 0.f ? y0 : 0.2f * y0) * 1.4142135623730951f;
            y1 = (y1 > 0.f ? y1 : 0.2f * y1) * 1.4142135623730951f;
            y2 = (y2 > 0.f ? y2 : 0.2f * y2) * 1.4142135623730951f;
            y3 = (y3 > 0.f ? y3 : 0.2f * y3) * 1.4142135623730951f;
            int lp0 = kg * 2;
            tokens[((size_t)(b * NL + lp0)) * NPIX + pbase] = packbf(y0, y1);
            tokens[((size_t)(b * NL + lp0 + 1)) * NPIX + pbase] = packbf(y2, y3);
        }
        {
            float y0 = a1[0] * dc[1][0] + bs[1][0];
            float y1 = a1[1] * dc[1][1] + bs[1][1];
            float y2 = a1[2] * dc[1][2] + bs[1][2];
            float y3 = a1[3] * dc[1][3] + bs[1][3];
            y0 = (y0 > 0.f ? y0 : 0.2f * y0) * 1.4142135623730951f;
            y1 = (y1 > 0.f ? y1 : 0.2f * y1) * 1.4142135623730951f;
            y2 = (y2 > 0.f ? y2 : 0.2f * y2) * 1.4142135623730951f;
            y3 = (y3 > 0.f ? y3 : 0.2f * y3) * 1.4142135623730951f;
            int lp0 = 8 + kg * 2;
            tokens[((size_t)(b * NL + lp0)) * NPIX + pbase] = packbf(y0, y1);
            tokens[((size_t)(b * NL + lp0 + 1)) * NPIX + pbase] = packbf(y2, y3);
        }
    }
}

// ---- K3a: recon stage 1, LDS-staged — block = (l, 4 rows); wave = one row ----
__global__ __launch_bounds__(256) void k_recon1(const uint32_t* __restrict__ tokens,
                                                const int* __restrict__ ctab,
                                                const float* __restrict__ ftab,
                                                const int* __restrict__ stab,
                                                uint32_t* __restrict__ U, LevelParams p) {
    __shared__ float2 cf[256];                 // (cell as int-bits, frac) per pixel col
    __shared__ int sl[260];                    // lower-bound table S[0..r]
    __shared__ uint32_t tok[4][256];           // 4 token rows (bf16x2)
    int l = blockIdx.x >> 6;
    int grp = blockIdx.x & 63;
    int b = blockIdx.y;
    int tid = threadIdx.x;
    int lane = tid & 63, wv = tid >> 6;
    int r = p.res[l];

    cf[tid] = make_float2(__int_as_float(ctab[l * 256 + tid]), ftab[l * 256 + tid]);
    for (int q = tid; q <= r; q += 256) sl[q] = stab[p.soff[l] + q];
    int i = grp * 4 + wv;
    const uint32_t* trow = tokens + (size_t)(b * NL + l) * NPIX + i * 256;
    *(uint4*)&tok[wv][lane * 4] = *(const uint4*)(trow + lane * 4);
    __syncthreads();

    uint32_t* Ul = U + (size_t)b * (p.sumr * 256) + p.uoff[l] + (size_t)i * r;
    int nck = p.nck[l];
    #pragma unroll 1
    for (int ck = 0; ck < nck; ++ck) {
        int cx = ck * 64 + lane;
        bool valid = cx < r;
        int jlo = 0, jhi = -1;
        if (valid) {
            jlo = (cx > 0) ? sl[cx - 1] : 0;
            jhi = sl[min(cx + 1, r)] - 1;
        }
        float a0 = 0.f, a1 = 0.f;
        for (int j = jlo; j <= jhi; ++j) {
            float2 cfv = cf[j];
            int c = __float_as_int(cfv.x);
            float f = cfv.y;
            float w = (c == cx) ? (1.f - f) : f;
            uint32_t tv = tok[wv][j];
            a0 += w * bflo(tv);
            a1 += w * bfhi(tv);
        }
        if (valid)
            Ul[cx] = packh2(a0, a1);
    }
}

// ---- K3b: recon stage 2 — wave per (level, cy, 64-wide cx chunk) ----
__global__ __launch_bounds__(256) void k_recon2(const uint32_t* __restrict__ U,
                                                const int* __restrict__ ctab,
                                                const float* __restrict__ ftab,
                                                const int* __restrict__ stab,
                                                float* __restrict__ R, LevelParams p) {
    int wid = blockIdx.x * 4 + (threadIdx.x >> 6);
    int lane = threadIdx.x & 63;
    int b = blockIdx.y;
    if (wid >= p.nwaves) return;
    int l = 0;
    #pragma unroll
    for (int q = 1; q < NL; ++q) if (wid >= p.cwoff[q]) l = q;
    int u = wid - p.cwoff[l];
    int r = p.res[l];
    int nck = p.nck[l];
    int cy = u / nck;
    int ck = u - cy * nck;
    int cx = ck * 64 + lane;
    bool valid = cx < r;
    const int* Sl = stab + p.soff[l];
    int ilo = (cy > 0) ? Sl[cy - 1] : 0;
    int ihi = Sl[min(cy + 1, r)] - 1;
    const uint32_t* Ub = U + (size_t)b * (p.sumr * 256) + p.uoff[l];
    const int* crow = ctab + l * 256;
    const float* frow = ftab + l * 256;
    float a0 = 0.f, a1 = 0.f;
    for (int i = ilo; i <= ihi; ++i) {
        int c = crow[i];
        float f = frow[i];
        float w = (c == cy) ? (1.f - f) : f;
        if (valid) {
            uint32_t uu = Ub[(size_t)i * r + cx];
            a0 += w * h2lo(uu);
            a1 += w * h2hi(uu);
        }
    }
    if (!valid) return;
    float* Rbl = R + (size_t)(b * NL + l) * TD * 2;
    if (p.hashed[l]) {
        uint32_t h = ((uint32_t)cx ^ ((uint32_t)cy * PRIME)) & (TD - 1);
        atomicAdd(&Rbl[2 * h], a0);
        atomicAdd(&Rbl[2 * h + 1], a1);
    } else {
        *(float2*)(Rbl + 2 * (cy * r + cx)) = make_float2(a0, a1);
    }
}

// ---- K4: residual + LayerNorm(16384) -> FP32 out ----
__global__ __launch_bounds__(512) void k_ln(const float* __restrict__ R,
                                            const float* __restrict__ inp,
                                            float* __restrict__ out) {
    int row = blockIdx.x;                       // b*NL + l
    const float4* rv = (const float4*)(R + (size_t)row * 16384);
    const float4* iv = (const float4*)(inp + (size_t)row * 16384);
    int tid = threadIdx.x;
    float sum = 0.f, ssq = 0.f;
    for (int k = tid; k < 4096; k += 512) {
        float4 a = rv[k], c = iv[k];
        float x0 = a.x + c.x, x1 = a.y + c.y, x2 = a.z + c.z, x3 = a.w + c.w;
        sum += x0 + x1 + x2 + x3;
        ssq += x0 * x0 + x1 * x1 + x2 * x2 + x3 * x3;
    }
    #pragma unroll
    for (int off = 32; off > 0; off >>= 1) {
        sum += __shfl_xor(sum, off, 64);
        ssq += __shfl_xor(ssq, off, 64);
    }
    __shared__ float red[16];
    int w = tid >> 6;
    if ((tid & 63) == 0) { red[w * 2] = sum; red[w * 2 + 1] = ssq; }
    __syncthreads();
    sum = 0.f; ssq = 0.f;
    #pragma unroll
    for (int q = 0; q < 8; ++q) { sum += red[q * 2]; ssq += red[q * 2 + 1]; }
    float mu = sum * (1.f / 16384.f);
    float var = ssq * (1.f / 16384.f) - mu * mu;
    float inv = rsqrtf(var + 1e-5f);
    float4* ob = (float4*)(out + (size_t)row * 16384);
    for (int k = tid; k < 4096; k += 512) {
        float4 a = rv[k], c = iv[k];
        float4 o4;
        o4.x = (a.x + c.x - mu) * inv;
        o4.y = (a.y + c.y - mu) * inv;
        o4.z = (a.z + c.z - mu) * inv;
        o4.w = (a.w + c.w - mu) * inv;
        ob[k] = o4;
    }
}

extern "C" void kernel_launch(void* const* d_in, const int* in_sizes, int n_in,
                              void* d_out, int out_size, void* d_ws, size_t ws_size,
                              hipStream_t stream) {
    const float* inputs = (const float*)d_in[0];
    const float* s      = (const float*)d_in[1];
    const float* coords = (const float*)d_in[2];
    const float* aw     = (const float*)d_in[3];
    const float* ab     = (const float*)d_in[4];
    const float* cw     = (const float*)d_in[5];
    const float* cb     = (const float*)d_in[6];

    char* ws = (char*)d_ws;
    uint32_t* U      = (uint32_t*)(ws);                 // 11.7 MB used (fp16x2 packed)
    uint32_t* tokens = (uint32_t*)(ws + 33554432);      // 33,554,432 B
    float*    R      = (float*)(ws + 67108864);         //  8,388,608 B
    float*    styles = (float*)(ws + 75497472);         // 1 KB
    float*    dcoef  = (float*)(ws + 75498496);         // 1 KB
    int*      ctab   = (int*)(ws + 75499520);           // 16 KB
    float*    ftab   = (float*)(ws + 75515904);         // 16 KB
    int*      stab   = (int*)(ws + 75532288);           // 8 KB
    unsigned short* wpack = (unsigned short*)(ws + 75540480); // 18.4 KB

    // RES_LIST exactly as numpy computes it (double libm ops).
    LevelParams p;
    double bb = exp((log(256.0) - log(16.0)) / 15.0);
    int uoff = 0, soff = 0, cwoff = 0, sumr = 0;
    for (int l = 0; l < NL; ++l) {
        int r = (int)floor(16.0 * pow(bb, (double)l));
        p.res[l] = r;
        p.hashed[l] = (r * r > TD) ? 1 : 0;
        p.uoff[l] = uoff;
        p.soff[l] = soff;
        p.cwoff[l] = cwoff;
        int nck = (r + 63) >> 6;
        p.nck[l] = nck;
        uoff += r * 256;
        soff += r + 2;
        cwoff += r * nck;
        sumr += r;
    }
    p.sumr = sumr;
    p.nwaves = cwoff;

    hipMemsetAsync(R, 0, (size_t)NB * NL * TD * 2 * sizeof(float), stream);
    hipLaunchKernelGGL(k_prep, dim3(NB + NL + 36), dim3(256), 0, stream,
                       s, aw, ab, cw, coords, styles, dcoef, ctab, ftab, stab, wpack, p);
    // ---- DIAGNOSTIC ablations (write garbage into tokens; real conv overwrites) ----
    hipLaunchKernelGGL(k_conv_ab1, dim3(2048), dim3(256), 0, stream,
                       inputs, ctab, ftab, styles, tokens, p);
    hipLaunchKernelGGL(k_conv_ab2, dim3(2048), dim3(256), 0, stream,
                       inputs, ctab, ftab, styles, tokens, p);
    hipLaunchKernelGGL(k_conv, dim3(2048), dim3(256), 0, stream,
                       inputs, ctab, ftab, styles, wpack, cb, dcoef, tokens, p);
    hipLaunchKernelGGL(k_recon1, dim3(NL * 64, NB), dim3(256), 0, stream,
                       tokens, ctab, ftab, stab, U, p);
    hipLaunchKernelGGL(k_recon2, dim3((p.nwaves + 3) / 4, NB), dim3(256), 0, stream,
                       U, ctab, ftab, stab, R, p);
    hipLaunchKernelGGL(k_ln, dim3(NB * NL), dim3(512), 0, stream,
                       R, inputs, (float*)d_out);
}

// Round 18
// 121.442 us; speedup vs baseline: 1.3410x; 1.3410x over previous
//
#include <hip/hip_runtime.h>
#include <hip/hip_fp16.h>
#include <cmath>
#include <cstdint>

#define NB 8
#define NL 16
#define TD 8192
#define NPIX 65536
#define CH 32
#define SD 512

static constexpr uint32_t PRIME = 2654435761u;

typedef __attribute__((ext_vector_type(8))) short bf16x8;
typedef __attribute__((ext_vector_type(4))) float f32x4;

// per-level corner-tile capacities for a 16x16 tile (+halo, 17-px span)
static constexpr int cNCX[16] = {4,5,5,5,6,6,7,7,8,9,10,12,13,15,18,20};
static constexpr int CTOFF[17] = {0,16,41,66,91,127,163,212,261,325,406,506,650,819,1044,1368,1768};

struct LevelParams {
    int res[NL];
    int hashed[NL];
    int uoff[NL];    // prefix of 256*r u32 (per batch) into packed U [i][cx]
    int soff[NL];    // prefix of (r+2) ints into stab
    int cwoff[NL];   // recon2 wave prefix (r*nck)
    int nck[NL];     // ceil(r/64)
    int sumr;
    int nwaves;      // recon2 waves per batch
};

// ---- bf16 helpers (RNE) ----
__device__ __forceinline__ unsigned short f2bf(float f) {
    uint32_t u = __float_as_uint(f);
    return (unsigned short)((u + 0x7fffu + ((u >> 16) & 1u)) >> 16);
}
__device__ __forceinline__ float bflo(uint32_t u) { return __uint_as_float(u << 16); }
__device__ __forceinline__ float bfhi(uint32_t u) { return __uint_as_float(u & 0xffff0000u); }
__device__ __forceinline__ uint32_t packbf(float a, float b) {
    return (uint32_t)f2bf(a) | ((uint32_t)f2bf(b) << 16);
}
// ---- fp16x2 pack helpers for U ----
__device__ __forceinline__ uint32_t packh2(float a, float b) {
    return (uint32_t)__half_as_ushort(__float2half_rn(a)) |
           ((uint32_t)__half_as_ushort(__float2half_rn(b)) << 16);
}
__device__ __forceinline__ float h2lo(uint32_t u) {
    return __half2float(__ushort_as_half((unsigned short)(u & 0xffffu)));
}
__device__ __forceinline__ float h2hi(uint32_t u) {
    return __half2float(__ushort_as_half((unsigned short)(u >> 16)));
}

// ---- K_prep: styles+dcoef (blocks 0..7), wtab (8..23), wpack (24..59) ----
__global__ __launch_bounds__(256) void k_prep(
    const float* __restrict__ s, const float* __restrict__ aw,
    const float* __restrict__ ab, const float* __restrict__ cw,
    const float* __restrict__ coords,
    float* __restrict__ styles, float* __restrict__ dcoef,
    int* __restrict__ ctab, float* __restrict__ ftab, int* __restrict__ stab,
    unsigned short* __restrict__ wpack, LevelParams p) {
    int bb = blockIdx.x;
    int t = threadIdx.x;
    if (bb < NB) {
        int b = bb;
        int c = t >> 3, part = t & 7;               // 32 ch x 8 parts
        const float* sv = s + b * SD + part * 64;
        const float* wv = aw + c * SD + part * 64;
        float acc = 0.f;
        #pragma unroll 8
        for (int k = 0; k < 64; ++k) acc += sv[k] * wv[k];
        acc += __shfl_xor(acc, 1, 64);
        acc += __shfl_xor(acc, 2, 64);
        acc += __shfl_xor(acc, 4, 64);
        __shared__ float st_sh[CH];
        if (part == 0) {
            float st = acc * 0.04419417382415922f /* 1/sqrt(512) */ + ab[c];
            styles[b * CH + c] = st;
            st_sh[c] = st;
        }
        __syncthreads();
        if (t < CH) {
            float d = 0.f;
            for (int i = 0; i < CH; ++i) {
                const float* w9 = cw + (t * CH + i) * 9;
                float ws = 0.f;
                #pragma unroll
                for (int k = 0; k < 9; ++k) ws += w9[k] * w9[k];
                float si = st_sh[i];
                d += ws * si * si;
            }
            dcoef[b * CH + t] = rsqrtf(d + 1e-8f);
        }
    } else if (bb < NB + NL) {
        int l = bb - NB;
        int j = t;
        int r = p.res[l];
        float g = coords[2 * j];                   // x-coord of col j == y-coord of row j
        float px = g * (float)(r - 1);
        float fl = floorf(px);
        float f = px - fl;
        int c = min((int)fl, r - 2);
        ctab[l * 256 + j] = c;
        ftab[l * 256 + j] = f;
        __shared__ int cs[256];
        cs[j] = c;
        __syncthreads();
        for (int cc = j; cc <= r; cc += 256) {
            int cnt = 0;
            for (int i = 0; i < 256; ++i) cnt += (cs[i] < cc) ? 1 : 0;
            stab[p.soff[l] + cc] = cnt;
        }
    } else {
        int idx = (bb - NB - NL) * 256 + t;
        if (idx < 9 * 4 * 32 * 8) {
            int j = idx & 7;
            int o = (idx >> 3) & 31;
            int kgi = (idx >> 8) & 3;
            int tap = idx >> 10;
            wpack[idx] = f2bf(cw[(o * 32 + kgi * 8 + j) * 9 + tap]);
        }
    }
}

// ---- fused retrieve feature from (cell-rel,frac) + LDS corners ----
template<int L>
__device__ __forceinline__ uint32_t feat1p(float2 cv, float2 rv, const uint32_t* ctile) {
    int a = CTOFF[L] + __float_as_int(rv.x) * cNCX[L] + __float_as_int(cv.x);
    float fx = cv.y, fy = rv.y;
    uint32_t c00 = ctile[a], c10 = ctile[a + 1];             // ds_read2_b32
    uint32_t c01 = ctile[a + cNCX[L]], c11 = ctile[a + cNCX[L] + 1];
    float w00 = (1.f - fx) * (1.f - fy), w10 = fx * (1.f - fy);
    float w01 = (1.f - fx) * fy,         w11 = fx * fy;
    float f0 = w00 * bflo(c00) + w10 * bflo(c10) + w01 * bflo(c01) + w11 * bflo(c11);
    float f1 = w00 * bfhi(c00) + w10 * bfhi(c10) + w01 * bfhi(c01) + w11 * bfhi(c11);
    return packbf(f0, f1);
}

// ---- phase 1: one wave = 4 levels, all 324 halo px ----
template<int L0>
__device__ __forceinline__ void phase1(int lane, int tx0, int ty0,
                                       const float2* col2, const float2* row2,
                                       const uint32_t* ctile, uint32_t* xt) {
    constexpr int q = L0 / 4;
    #pragma unroll
    for (int it = 0; it < 6; ++it) {
        int pl = it * 64 + lane;
        int rr = pl / 18, cc = pl - rr * 18;
        int gy = ty0 + rr - 1, gx = tx0 + cc - 1;
        uint4 v = make_uint4(0u, 0u, 0u, 0u);
        if (pl < 324 && (unsigned)gy < 256u && (unsigned)gx < 256u) {
            float2 cv0 = col2[(L0 + 0) * 18 + cc], rv0 = row2[(L0 + 0) * 18 + rr];
            float2 cv1 = col2[(L0 + 1) * 18 + cc], rv1 = row2[(L0 + 1) * 18 + rr];
            float2 cv2 = col2[(L0 + 2) * 18 + cc], rv2 = row2[(L0 + 2) * 18 + rr];
            float2 cv3 = col2[(L0 + 3) * 18 + cc], rv3 = row2[(L0 + 3) * 18 + rr];
            v.x = feat1p<L0 + 0>(cv0, rv0, ctile);
            v.y = feat1p<L0 + 1>(cv1, rv1, ctile);
            v.z = feat1p<L0 + 2>(cv2, rv2, ctile);
            v.w = feat1p<L0 + 3>(cv3, rv3, ctile);
        }
        if (pl < 324)
            *(uint4*)(xt + (size_t)(pl * 4 + (q ^ (cc & 3))) * 4) = v;
    }
}

// ---- K2: FUSED retrieve+mod+MFMA conv, TWO BATCHES per block ----
// block = one 16x16 tile x batch-pair; grid 1024. 256 thr.
__global__ __launch_bounds__(256) void k_conv(
    const float* __restrict__ tables, const int* __restrict__ ctab,
    const float* __restrict__ ftab, const float* __restrict__ styles,
    const unsigned short* __restrict__ wpack, const float* __restrict__ cb,
    const float* __restrict__ dcoef, uint32_t* __restrict__ tokens,
    LevelParams p) {
    __shared__ uint32_t xt[18 * 18 * 16];      // 20736 B (reused per batch)
    __shared__ uint32_t ctile2[2][1768];       // 14144 B premod corners, 2 batches
    __shared__ float2 col2[NL * 18];           // 2304 B
    __shared__ float2 row2[NL * 18];           // 2304 B
    __shared__ int cxbase[NL], cybase[NL], ncxA[NL], ncyA[NL];

    int bid = blockIdx.x;                      // 1024
    int pb = bid & 3;                          // batch pair -> b0=2pb, b0+1
    int t = bid >> 2;                          // tile 0..255
    int b0 = pb * 2;
    int tx0 = (t & 15) * 16, ty0 = (t >> 4) * 16;
    int tid = threadIdx.x;
    int lane = tid & 63, wv = tid >> 6;        // 4 waves
    int npx = lane & 15, kg = lane >> 4;
    const float* tbA = tables + (size_t)b0 * NL * TD * 2;
    const float* tbB = tbA + (size_t)NL * TD * 2;

    // ---- phase 0a: per-level corner-tile extents (batch-independent) ----
    if (tid < NL) {
        int l = tid;
        int cxb = ctab[l * 256 + max(tx0 - 1, 0)];
        int cyb = ctab[l * 256 + max(ty0 - 1, 0)];
        cxbase[l] = cxb;
        cybase[l] = cyb;
        ncxA[l] = ctab[l * 256 + min(tx0 + 16, 255)] - cxb + 2;
        ncyA[l] = ctab[l * 256 + min(ty0 + 16, 255)] - cyb + 2;
    }
    __syncthreads();

    // ---- phase 0b-i: col2/row2 (cell-rel, frac) — batch-independent ----
    for (int u0 = tid; u0 < NL * 36; u0 += 256) {
        int l = u0 / 36, pos = u0 - l * 36;
        if (pos < 18) {
            int gx = tx0 - 1 + pos;
            int gxc = min(max(gx, 0), 255);
            col2[l * 18 + pos] = make_float2(
                __int_as_float(ctab[l * 256 + gxc] - cxbase[l]), ftab[l * 256 + gxc]);
        } else {
            int pr = pos - 18;
            int gy = ty0 - 1 + pr;
            int gyc = min(max(gy, 0), 255);
            row2[l * 18 + pr] = make_float2(
                __int_as_float(ctab[l * 256 + gyc] - cybase[l]), ftab[l * 256 + gyc]);
        }
    }

    // ---- phase 0b-ii: gather corners for BOTH batches (shared index math) ----
    #pragma unroll
    for (int l = 0; l < NL; ++l) {
        const int NCXl = cNCX[l];
        const int CAP = (CTOFF[l + 1] - CTOFF[l]);
        float sA0 = styles[b0 * CH + 2 * l],       sA1 = styles[b0 * CH + 2 * l + 1];
        float sB0 = styles[(b0 + 1) * CH + 2 * l], sB1 = styles[(b0 + 1) * CH + 2 * l + 1];
        for (int u2 = tid; u2 < CAP; u2 += 256) {
            int sy = u2 / NCXl;
            int sx = u2 - sy * NCXl;
            if (sx < ncxA[l] && sy < ncyA[l]) {
                int ax = cxbase[l] + sx, ay = cybase[l] + sy;
                int r = p.res[l];
                uint32_t idx = p.hashed[l]
                    ? (((uint32_t)ax ^ ((uint32_t)ay * PRIME)) & (TD - 1))
                    : (uint32_t)(ay * r + ax);
                float2 gA = *(const float2*)(tbA + (size_t)l * TD * 2 + 2 * idx);
                float2 gB = *(const float2*)(tbB + (size_t)l * TD * 2 + 2 * idx);
                ctile2[0][CTOFF[l] + sy * NCXl + sx] = packbf(gA.x * sA0, gA.y * sA1);
                ctile2[1][CTOFF[l] + sy * NCXl + sx] = packbf(gB.x * sB0, gB.y * sB1);
            }
        }
    }

    // ---- weights (batch-independent) + bias; demod per batch ----
    bf16x8 wf[9][2];
    #pragma unroll
    for (int tp = 0; tp < 9; ++tp) {
        wf[tp][0] = *(const bf16x8*)(wpack + (size_t)((tp * 4 + kg) * 32 + npx) * 8);
        wf[tp][1] = *(const bf16x8*)(wpack + (size_t)((tp * 4 + kg) * 32 + 16 + npx) * 8);
    }
    float bs[2][4];
    #pragma unroll
    for (int ob = 0; ob < 2; ++ob)
        #pragma unroll
        for (int rg = 0; rg < 4; ++rg)
            bs[ob][rg] = cb[ob * 16 + kg * 4 + rg];
    float dcA[2][4], dcB[2][4];
    #pragma unroll
    for (int ob = 0; ob < 2; ++ob)
        #pragma unroll
        for (int rg = 0; rg < 4; ++rg) {
            int oc = ob * 16 + kg * 4 + rg;
            dcA[ob][rg] = dcoef[b0 * CH + oc];
            dcB[ob][rg] = dcoef[(b0 + 1) * CH + oc];
        }
    __syncthreads();

    // ---- per-batch: phase1 -> barrier -> phase2 -> barrier ----
    #pragma unroll
    for (int bb = 0; bb < 2; ++bb) {
        int b = b0 + bb;
        const uint32_t* ct = ctile2[bb];
        switch (wv) {
            case 0: phase1<0>(lane, tx0, ty0, col2, row2, ct, xt); break;
            case 1: phase1<4>(lane, tx0, ty0, col2, row2, ct, xt); break;
            case 2: phase1<8>(lane, tx0, ty0, col2, row2, ct, xt); break;
            default: phase1<12>(lane, tx0, ty0, col2, row2, ct, xt); break;
        }
        __syncthreads();

        #pragma unroll 1
        for (int it = 0; it < 4; ++it) {
            int py_l = it * 4 + wv;            // 16 rows
            int px_l = npx;
            f32x4 a0 = {0.f, 0.f, 0.f, 0.f};
            f32x4 a1 = {0.f, 0.f, 0.f, 0.f};
            #pragma unroll
            for (int ky = 0; ky < 3; ++ky) {
                int rowb = (py_l + ky) * 18;
                #pragma unroll
                for (int kx = 0; kx < 3; ++kx) {
                    int cc = px_l + kx;
                    bf16x8 bf = *(const bf16x8*)(xt + (((rowb + cc) << 2) + (kg ^ (cc & 3))) * 4);
                    a0 = __builtin_amdgcn_mfma_f32_16x16x32_bf16(wf[ky * 3 + kx][0], bf, a0, 0, 0, 0);
                    a1 = __builtin_amdgcn_mfma_f32_16x16x32_bf16(wf[ky * 3 + kx][1], bf, a1, 0, 0, 0);
                }
            }
            int py = ty0 + py_l, px = tx0 + px_l;
            size_t pbase = (size_t)py * 256 + px;
            const float (*dc)[4] = bb ? dcB : dcA;
            {
                float y0 = a0[0] * dc[0][0] + bs[0][0];
                float y1 = a0[1] * dc[0][1] + bs[0][1];
                float y2 = a0[2] * dc[0][2] + bs[0][2];
                float y3 = a0[3] * dc[0][3] + bs[0][3];
                y0 = (y0 > 0.f ? y0 : 0.2f * y0) * 1.4142135623730951f;
                y1 = (y1 > 0.f ? y1 : 0.2f * y1) * 1.4142135623730951f;
                y2 = (y2 > 0.f ? y2 : 0.2f * y2) * 1.4142135623730951f;
                y3 = (y3 > 0.f ? y3 : 0.2f * y3) * 1.4142135623730951f;
                int lp0 = kg * 2;
                tokens[((size_t)(b * NL + lp0)) * NPIX + pbase] = packbf(y0, y1);
                tokens[((size_t)(b * NL + lp0 + 1)) * NPIX + pbase] = packbf(y2, y3);
            }
            {
                float y0 = a1[0] * dc[1][0] + bs[1][0];
                float y1 = a1[1] * dc[1][1] + bs[1][1];
                float y2 = a1[2] * dc[1][2] + bs[1][2];
                float y3 = a1[3] * dc[1][3] + bs[1][3];
                y0 = (y0 > 0.f ? y0 : 0.2f * y0) * 1.4142135623730951f;
                y1 = (y1 > 0.f ? y1 : 0.2f * y1) * 1.4142135623730951f;
                y2 = (y2 > 0.f ? y2 : 0.2f * y2) * 1.4142135623730951f;
                y3 = (y3 > 0.f ? y3 : 0.2f * y3) * 1.4142135623730951f;
                int lp0 = 8 + kg * 2;
                tokens[((size_t)(b * NL + lp0)) * NPIX + pbase] = packbf(y0, y1);
                tokens[((size_t)(b * NL + lp0 + 1)) * NPIX + pbase] = packbf(y2, y3);
            }
        }
        __syncthreads();                       // xt reused by next batch
    }
}

// ---- K3a: recon stage 1, LDS-staged — block = (l, 4 rows); wave = one row ----
__global__ __launch_bounds__(256) void k_recon1(const uint32_t* __restrict__ tokens,
                                                const int* __restrict__ ctab,
                                                const float* __restrict__ ftab,
                                                const int* __restrict__ stab,
                                                uint32_t* __restrict__ U, LevelParams p) {
    __shared__ float2 cf[256];                 // (cell as int-bits, frac) per pixel col
    __shared__ int sl[260];                    // lower-bound table S[0..r]
    __shared__ uint32_t tok[4][256];           // 4 token rows (bf16x2)
    int l = blockIdx.x >> 6;
    int grp = blockIdx.x & 63;
    int b = blockIdx.y;
    int tid = threadIdx.x;
    int lane = tid & 63, wv = tid >> 6;
    int r = p.res[l];

    cf[tid] = make_float2(__int_as_float(ctab[l * 256 + tid]), ftab[l * 256 + tid]);
    for (int q = tid; q <= r; q += 256) sl[q] = stab[p.soff[l] + q];
    int i = grp * 4 + wv;
    const uint32_t* trow = tokens + (size_t)(b * NL + l) * NPIX + i * 256;
    *(uint4*)&tok[wv][lane * 4] = *(const uint4*)(trow + lane * 4);
    __syncthreads();

    uint32_t* Ul = U + (size_t)b * (p.sumr * 256) + p.uoff[l] + (size_t)i * r;
    int nck = p.nck[l];
    #pragma unroll 1
    for (int ck = 0; ck < nck; ++ck) {
        int cx = ck * 64 + lane;
        bool valid = cx < r;
        int jlo = 0, jhi = -1;
        if (valid) {
            jlo = (cx > 0) ? sl[cx - 1] : 0;
            jhi = sl[min(cx + 1, r)] - 1;
        }
        float a0 = 0.f, a1 = 0.f;
        for (int j = jlo; j <= jhi; ++j) {
            float2 cfv = cf[j];
            int c = __float_as_int(cfv.x);
            float f = cfv.y;
            float w = (c == cx) ? (1.f - f) : f;
            uint32_t tv = tok[wv][j];
            a0 += w * bflo(tv);
            a1 += w * bfhi(tv);
        }
        if (valid)
            Ul[cx] = packh2(a0, a1);
    }
}

// ---- K3b: recon stage 2 — wave per (level, cy, 64-wide cx chunk) ----
__global__ __launch_bounds__(256) void k_recon2(const uint32_t* __restrict__ U,
                                                const int* __restrict__ ctab,
                                                const float* __restrict__ ftab,
                                                const int* __restrict__ stab,
                                                float* __restrict__ R, LevelParams p) {
    int wid = blockIdx.x * 4 + (threadIdx.x >> 6);
    int lane = threadIdx.x & 63;
    int b = blockIdx.y;
    if (wid >= p.nwaves) return;
    int l = 0;
    #pragma unroll
    for (int q = 1; q < NL; ++q) if (wid >= p.cwoff[q]) l = q;
    int u = wid - p.cwoff[l];
    int r = p.res[l];
    int nck = p.nck[l];
    int cy = u / nck;
    int ck = u - cy * nck;
    int cx = ck * 64 + lane;
    bool valid = cx < r;
    const int* Sl = stab + p.soff[l];
    int ilo = (cy > 0) ? Sl[cy - 1] : 0;
    int ihi = Sl[min(cy + 1, r)] - 1;
    const uint32_t* Ub = U + (size_t)b * (p.sumr * 256) + p.uoff[l];
    const int* crow = ctab + l * 256;
    const float* frow = ftab + l * 256;
    float a0 = 0.f, a1 = 0.f;
    for (int i = ilo; i <= ihi; ++i) {
        int c = crow[i];
        float f = frow[i];
        float w = (c == cy) ? (1.f - f) : f;
        if (valid) {
            uint32_t uu = Ub[(size_t)i * r + cx];
            a0 += w * h2lo(uu);
            a1 += w * h2hi(uu);
        }
    }
    if (!valid) return;
    float* Rbl = R + (size_t)(b * NL + l) * TD * 2;
    if (p.hashed[l]) {
        uint32_t h = ((uint32_t)cx ^ ((uint32_t)cy * PRIME)) & (TD - 1);
        atomicAdd(&Rbl[2 * h], a0);
        atomicAdd(&Rbl[2 * h + 1], a1);
    } else {
        *(float2*)(Rbl + 2 * (cy * r + cx)) = make_float2(a0, a1);
    }
}

// ---- K4: residual + LayerNorm(16384) -> FP32 out ----
__global__ __launch_bounds__(512) void k_ln(const float* __restrict__ R,
                                            const float* __restrict__ inp,
                                            float* __restrict__ out) {
    int row = blockIdx.x;                       // b*NL + l
    const float4* rv = (const float4*)(R + (size_t)row * 16384);
    const float4* iv = (const float4*)(inp + (size_t)row * 16384);
    int tid = threadIdx.x;
    float sum = 0.f, ssq = 0.f;
    for (int k = tid; k < 4096; k += 512) {
        float4 a = rv[k], c = iv[k];
        float x0 = a.x + c.x, x1 = a.y + c.y, x2 = a.z + c.z, x3 = a.w + c.w;
        sum += x0 + x1 + x2 + x3;
        ssq += x0 * x0 + x1 * x1 + x2 * x2 + x3 * x3;
    }
    #pragma unroll
    for (int off = 32; off > 0; off >>= 1) {
        sum += __shfl_xor(sum, off, 64);
        ssq += __shfl_xor(ssq, off, 64);
    }
    __shared__ float red[16];
    int w = tid >> 6;
    if ((tid & 63) == 0) { red[w * 2] = sum; red[w * 2 + 1] = ssq; }
    __syncthreads();
    sum = 0.f; ssq = 0.f;
    #pragma unroll
    for (int q = 0; q < 8; ++q) { sum += red[q * 2]; ssq += red[q * 2 + 1]; }
    float mu = sum * (1.f / 16384.f);
    float var = ssq * (1.f / 16384.f) - mu * mu;
    float inv = rsqrtf(var + 1e-5f);
    float4* ob = (float4*)(out + (size_t)row * 16384);
    for (int k = tid; k < 4096; k += 512) {
        float4 a = rv[k], c = iv[k];
        float4 o4;
        o4.x = (a.x + c.x - mu) * inv;
        o4.y = (a.y + c.y - mu) * inv;
        o4.z = (a.z + c.z - mu) * inv;
        o4.w = (a.w + c.w - mu) * inv;
        ob[k] = o4;
    }
}

extern "C" void kernel_launch(void* const* d_in, const int* in_sizes, int n_in,
                              void* d_out, int out_size, void* d_ws, size_t ws_size,
                              hipStream_t stream) {
    const float* inputs = (const float*)d_in[0];
    const float* s      = (const float*)d_in[1];
    const float* coords = (const float*)d_in[2];
    const float* aw     = (const float*)d_in[3];
    const float* ab     = (const float*)d_in[4];
    const float* cw     = (const float*)d_in[5];
    const float* cb     = (const float*)d_in[6];

    char* ws = (char*)d_ws;
    uint32_t* U      = (uint32_t*)(ws);                 // 11.7 MB used (fp16x2 packed)
    uint32_t* tokens = (uint32_t*)(ws + 33554432);      // 33,554,432 B
    float*    R      = (float*)(ws + 67108864);         //  8,388,608 B
    float*    styles = (float*)(ws + 75497472);         // 1 KB
    float*    dcoef  = (float*)(ws + 75498496);         // 1 KB
    int*      ctab   = (int*)(ws + 75499520);           // 16 KB
    float*    ftab   = (float*)(ws + 75515904);         // 16 KB
    int*      stab   = (int*)(ws + 75532288);           // 8 KB
    unsigned short* wpack = (unsigned short*)(ws + 75540480); // 18.4 KB

    // RES_LIST exactly as numpy computes it (double libm ops).
    LevelParams p;
    double bb = exp((log(256.0) - log(16.0)) / 15.0);
    int uoff = 0, soff = 0, cwoff = 0, sumr = 0;
    for (int l = 0; l < NL; ++l) {
        int r = (int)floor(16.0 * pow(bb, (double)l));
        p.res[l] = r;
        p.hashed[l] = (r * r > TD) ? 1 : 0;
        p.uoff[l] = uoff;
        p.soff[l] = soff;
        p.cwoff[l] = cwoff;
        int nck = (r + 63) >> 6;
        p.nck[l] = nck;
        uoff += r * 256;
        soff += r + 2;
        cwoff += r * nck;
        sumr += r;
    }
    p.sumr = sumr;
    p.nwaves = cwoff;

    hipMemsetAsync(R, 0, (size_t)NB * NL * TD * 2 * sizeof(float), stream);
    hipLaunchKernelGGL(k_prep, dim3(NB + NL + 36), dim3(256), 0, stream,
                       s, aw, ab, cw, coords, styles, dcoef, ctab, ftab, stab, wpack, p);
    hipLaunchKernelGGL(k_conv, dim3(1024), dim3(256), 0, stream,
                       inputs, ctab, ftab, styles, wpack, cb, dcoef, tokens, p);
    hipLaunchKernelGGL(k_recon1, dim3(NL * 64, NB), dim3(256), 0, stream,
                       tokens, ctab, ftab, stab, U, p);
    hipLaunchKernelGGL(k_recon2, dim3((p.nwaves + 3) / 4, NB), dim3(256), 0, stream,
                       U, ctab, ftab, stab, R, p);
    hipLaunchKernelGGL(k_ln, dim3(NB * NL), dim3(512), 0, stream,
                       R, inputs, (float*)d_out);
}

// Round 19
// 110.100 us; speedup vs baseline: 1.4791x; 1.1030x over previous
//
#include <hip/hip_runtime.h>
#include <hip/hip_fp16.h>
#include <cmath>
#include <cstdint>

#define NB 8
#define NL 16
#define TD 8192
#define NPIX 65536
#define CH 32
#define SD 512

static constexpr uint32_t PRIME = 2654435761u;

typedef __attribute__((ext_vector_type(8))) short bf16x8;
typedef __attribute__((ext_vector_type(4))) float f32x4;

// per-level corner-tile capacities for a 16x16 tile (+halo, 17-px span)
static constexpr int cNCX[16] = {4,5,5,5,6,6,7,7,8,9,10,12,13,15,18,20};
static constexpr int CTOFF[17] = {0,16,41,66,91,127,163,212,261,325,406,506,650,819,1044,1368,1768};

struct LevelParams {
    int res[NL];
    int hashed[NL];
    int uoff[NL];    // prefix of 256*r u32 (per batch) into packed U [i][cx]
    int soff[NL];    // prefix of (r+2) ints into stab
    int cwoff[NL];   // recon2 wave prefix (r*nck)
    int nck[NL];     // ceil(r/64)
    int sumr;
    int nwaves;      // recon2 waves per batch
};

// ---- bf16 helpers (RNE) ----
__device__ __forceinline__ unsigned short f2bf(float f) {
    uint32_t u = __float_as_uint(f);
    return (unsigned short)((u + 0x7fffu + ((u >> 16) & 1u)) >> 16);
}
__device__ __forceinline__ float bflo(uint32_t u) { return __uint_as_float(u << 16); }
__device__ __forceinline__ float bfhi(uint32_t u) { return __uint_as_float(u & 0xffff0000u); }
__device__ __forceinline__ uint32_t packbf(float a, float b) {
    return (uint32_t)f2bf(a) | ((uint32_t)f2bf(b) << 16);
}
// ---- fp16x2 pack helpers for U ----
__device__ __forceinline__ uint32_t packh2(float a, float b) {
    return (uint32_t)__half_as_ushort(__float2half_rn(a)) |
           ((uint32_t)__half_as_ushort(__float2half_rn(b)) << 16);
}
__device__ __forceinline__ float h2lo(uint32_t u) {
    return __half2float(__ushort_as_half((unsigned short)(u & 0xffffu)));
}
__device__ __forceinline__ float h2hi(uint32_t u) {
    return __half2float(__ushort_as_half((unsigned short)(u >> 16)));
}

// ---- K_prep: styles+dcoef (blocks 0..7), wtab (8..23), wpack (24..59) ----
__global__ __launch_bounds__(256) void k_prep(
    const float* __restrict__ s, const float* __restrict__ aw,
    const float* __restrict__ ab, const float* __restrict__ cw,
    const float* __restrict__ coords,
    float* __restrict__ styles, float* __restrict__ dcoef,
    int* __restrict__ ctab, float* __restrict__ ftab, int* __restrict__ stab,
    unsigned short* __restrict__ wpack, LevelParams p) {
    int bb = blockIdx.x;
    int t = threadIdx.x;
    if (bb < NB) {
        int b = bb;
        int c = t >> 3, part = t & 7;               // 32 ch x 8 parts
        const float* sv = s + b * SD + part * 64;
        const float* wv = aw + c * SD + part * 64;
        float acc = 0.f;
        #pragma unroll 8
        for (int k = 0; k < 64; ++k) acc += sv[k] * wv[k];
        acc += __shfl_xor(acc, 1, 64);
        acc += __shfl_xor(acc, 2, 64);
        acc += __shfl_xor(acc, 4, 64);
        __shared__ float st_sh[CH];
        if (part == 0) {
            float st = acc * 0.04419417382415922f /* 1/sqrt(512) */ + ab[c];
            styles[b * CH + c] = st;
            st_sh[c] = st;
        }
        __syncthreads();
        if (t < CH) {
            float d = 0.f;
            for (int i = 0; i < CH; ++i) {
                const float* w9 = cw + (t * CH + i) * 9;
                float ws = 0.f;
                #pragma unroll
                for (int k = 0; k < 9; ++k) ws += w9[k] * w9[k];
                float si = st_sh[i];
                d += ws * si * si;
            }
            dcoef[b * CH + t] = rsqrtf(d + 1e-8f);
        }
    } else if (bb < NB + NL) {
        int l = bb - NB;
        int j = t;
        int r = p.res[l];
        float g = coords[2 * j];                   // x-coord of col j == y-coord of row j
        float px = g * (float)(r - 1);
        float fl = floorf(px);
        float f = px - fl;
        int c = min((int)fl, r - 2);
        ctab[l * 256 + j] = c;
        ftab[l * 256 + j] = f;
        __shared__ int cs[256];
        cs[j] = c;
        __syncthreads();
        for (int cc = j; cc <= r; cc += 256) {
            int cnt = 0;
            for (int i = 0; i < 256; ++i) cnt += (cs[i] < cc) ? 1 : 0;
            stab[p.soff[l] + cc] = cnt;
        }
    } else {
        int idx = (bb - NB - NL) * 256 + t;
        if (idx < 9 * 4 * 32 * 8) {
            int j = idx & 7;
            int o = (idx >> 3) & 31;
            int kgi = (idx >> 8) & 3;
            int tap = idx >> 10;
            wpack[idx] = f2bf(cw[(o * 32 + kgi * 8 + j) * 9 + tap]);
        }
    }
}

// ---- K_gather: pre-gather deduped premod corner tiles per (tile,batch) ----
// Same bid->(b,t) mapping as k_conv (XCD L2 locality). Coalesced stores.
__global__ __launch_bounds__(256) void k_gather(
    const float* __restrict__ tables, const int* __restrict__ ctab,
    const float* __restrict__ styles, uint32_t* __restrict__ ctileG,
    LevelParams p) {
    __shared__ int cxbase[NL], cybase[NL], ncxA[NL], ncyA[NL];
    int bid = blockIdx.x;                      // 2048
    int b = bid & 7;
    int t = bid >> 3;
    int tx0 = (t & 15) * 16, ty0 = (t >> 4) * 16;
    int tid = threadIdx.x;
    const float* tb = tables + (size_t)b * NL * TD * 2;
    if (tid < NL) {
        int l = tid;
        int cxb = ctab[l * 256 + max(tx0 - 1, 0)];
        int cyb = ctab[l * 256 + max(ty0 - 1, 0)];
        cxbase[l] = cxb;
        cybase[l] = cyb;
        ncxA[l] = ctab[l * 256 + min(tx0 + 16, 255)] - cxb + 2;
        ncyA[l] = ctab[l * 256 + min(ty0 + 16, 255)] - cyb + 2;
    }
    __syncthreads();
    uint32_t* out = ctileG + (size_t)bid * 1768;
    #pragma unroll
    for (int l = 0; l < NL; ++l) {
        const int NCXl = cNCX[l];
        const int CAP = (CTOFF[l + 1] - CTOFF[l]);
        float s0 = styles[b * CH + 2 * l], s1 = styles[b * CH + 2 * l + 1];
        for (int u2 = tid; u2 < CAP; u2 += 256) {
            int sy = u2 / NCXl;
            int sx = u2 - sy * NCXl;
            uint32_t val = 0u;
            if (sx < ncxA[l] && sy < ncyA[l]) {
                int ax = cxbase[l] + sx, ay = cybase[l] + sy;
                int r = p.res[l];
                uint32_t idx = p.hashed[l]
                    ? (((uint32_t)ax ^ ((uint32_t)ay * PRIME)) & (TD - 1))
                    : (uint32_t)(ay * r + ax);
                float2 g = *(const float2*)(tb + (size_t)l * TD * 2 + 2 * idx);
                val = packbf(g.x * s0, g.y * s1);
            }
            out[CTOFF[l] + u2] = val;          // coalesced
        }
    }
}

// ---- fused retrieve feature from (cell-rel,frac) + LDS corners ----
template<int L>
__device__ __forceinline__ uint32_t feat1p(float2 cv, float2 rv, const uint32_t* ctile) {
    int a = CTOFF[L] + __float_as_int(rv.x) * cNCX[L] + __float_as_int(cv.x);
    float fx = cv.y, fy = rv.y;
    uint32_t c00 = ctile[a], c10 = ctile[a + 1];             // ds_read2_b32
    uint32_t c01 = ctile[a + cNCX[L]], c11 = ctile[a + cNCX[L] + 1];
    float w00 = (1.f - fx) * (1.f - fy), w10 = fx * (1.f - fy);
    float w01 = (1.f - fx) * fy,         w11 = fx * fy;
    float f0 = w00 * bflo(c00) + w10 * bflo(c10) + w01 * bflo(c01) + w11 * bflo(c11);
    float f1 = w00 * bfhi(c00) + w10 * bfhi(c10) + w01 * bfhi(c01) + w11 * bfhi(c11);
    return packbf(f0, f1);
}

// ---- phase 1: one wave = 4 levels, all 324 halo px ----
template<int L0>
__device__ __forceinline__ void phase1(int lane, int tx0, int ty0,
                                       const float2* col2, const float2* row2,
                                       const uint32_t* ctile, uint32_t* xt) {
    constexpr int q = L0 / 4;
    #pragma unroll
    for (int it = 0; it < 6; ++it) {
        int pl = it * 64 + lane;
        int rr = pl / 18, cc = pl - rr * 18;
        int gy = ty0 + rr - 1, gx = tx0 + cc - 1;
        uint4 v = make_uint4(0u, 0u, 0u, 0u);
        if (pl < 324 && (unsigned)gy < 256u && (unsigned)gx < 256u) {
            float2 cv0 = col2[(L0 + 0) * 18 + cc], rv0 = row2[(L0 + 0) * 18 + rr];
            float2 cv1 = col2[(L0 + 1) * 18 + cc], rv1 = row2[(L0 + 1) * 18 + rr];
            float2 cv2 = col2[(L0 + 2) * 18 + cc], rv2 = row2[(L0 + 2) * 18 + rr];
            float2 cv3 = col2[(L0 + 3) * 18 + cc], rv3 = row2[(L0 + 3) * 18 + rr];
            v.x = feat1p<L0 + 0>(cv0, rv0, ctile);
            v.y = feat1p<L0 + 1>(cv1, rv1, ctile);
            v.z = feat1p<L0 + 2>(cv2, rv2, ctile);
            v.w = feat1p<L0 + 3>(cv3, rv3, ctile);
        }
        if (pl < 324)
            *(uint4*)(xt + (size_t)(pl * 4 + (q ^ (cc & 3))) * 4) = v;
    }
}

// ---- K2: FUSED retrieve+mod+MFMA 3x3 conv; corners pre-gathered ----
__global__ __launch_bounds__(256) void k_conv(
    const uint32_t* __restrict__ ctileG, const int* __restrict__ ctab,
    const float* __restrict__ ftab,
    const unsigned short* __restrict__ wpack, const float* __restrict__ cb,
    const float* __restrict__ dcoef, uint32_t* __restrict__ tokens,
    LevelParams p) {
    __shared__ uint32_t xt[18 * 18 * 16];      // 20736 B feature tile (bf16x2 chunks)
    __shared__ uint32_t ctile[1768];           // 7072 B premod corners (bf16x2)
    __shared__ float2 col2[NL * 18];           // 2304 B (cell-rel, frac) per halo col
    __shared__ float2 row2[NL * 18];           // 2304 B per halo row
    __shared__ int cxbase[NL], cybase[NL];

    int bid = blockIdx.x;
    int b = bid & 7;
    int t = bid >> 3;
    int tx0 = (t & 15) * 16, ty0 = (t >> 4) * 16;
    int tid = threadIdx.x;
    int lane = tid & 63, wv = tid >> 6;        // 4 waves
    int npx = lane & 15, kg = lane >> 4;

    // ---- setup: extents + coalesced ctile load + col2/row2 ----
    if (tid < NL) {
        int l = tid;
        cxbase[l] = ctab[l * 256 + max(tx0 - 1, 0)];
        cybase[l] = ctab[l * 256 + max(ty0 - 1, 0)];
    }
    {
        const uint4* src = (const uint4*)(ctileG + (size_t)bid * 1768);
        for (int i = tid; i < 442; i += 256)
            *(uint4*)(ctile + i * 4) = src[i];
    }
    __syncthreads();
    for (int u0 = tid; u0 < NL * 36; u0 += 256) {
        int l = u0 / 36, pos = u0 - l * 36;
        if (pos < 18) {
            int gx = tx0 - 1 + pos;
            int gxc = min(max(gx, 0), 255);
            col2[l * 18 + pos] = make_float2(
                __int_as_float(ctab[l * 256 + gxc] - cxbase[l]), ftab[l * 256 + gxc]);
        } else {
            int pr = pos - 18;
            int gy = ty0 - 1 + pr;
            int gyc = min(max(gy, 0), 255);
            row2[l * 18 + pr] = make_float2(
                __int_as_float(ctab[l * 256 + gyc] - cybase[l]), ftab[l * 256 + gyc]);
        }
    }
    __syncthreads();

    // ---- phase 1: wave-uniform 4-level feature computation -> xt (all-LDS) ----
    switch (wv) {
        case 0: phase1<0>(lane, tx0, ty0, col2, row2, ctile, xt); break;
        case 1: phase1<4>(lane, tx0, ty0, col2, row2, ctile, xt); break;
        case 2: phase1<8>(lane, tx0, ty0, col2, row2, ctile, xt); break;
        default: phase1<12>(lane, tx0, ty0, col2, row2, ctile, xt); break;
    }
    __builtin_amdgcn_sched_barrier(0);         // keep wf loads out of phase-1 live range

    // ---- weights (prepacked bf16 fragments) + demod/bias ----
    bf16x8 wf[9][2];
    #pragma unroll
    for (int tp = 0; tp < 9; ++tp) {
        wf[tp][0] = *(const bf16x8*)(wpack + (size_t)((tp * 4 + kg) * 32 + npx) * 8);
        wf[tp][1] = *(const bf16x8*)(wpack + (size_t)((tp * 4 + kg) * 32 + 16 + npx) * 8);
    }
    float dc[2][4], bs[2][4];
    #pragma unroll
    for (int ob = 0; ob < 2; ++ob)
        #pragma unroll
        for (int rg = 0; rg < 4; ++rg) {
            int oc = ob * 16 + kg * 4 + rg;
            dc[ob][rg] = dcoef[b * CH + oc];
            bs[ob][rg] = cb[oc];
        }
    __syncthreads();

    // ---- phase 2: MFMA conv (4 iterations per wave; group = one 16-px row) ----
    #pragma unroll 1
    for (int it = 0; it < 4; ++it) {
        int py_l = it * 4 + wv;                // 16 rows
        int px_l = npx;
        f32x4 a0 = {0.f, 0.f, 0.f, 0.f};
        f32x4 a1 = {0.f, 0.f, 0.f, 0.f};
        #pragma unroll
        for (int ky = 0; ky < 3; ++ky) {
            int rowb = (py_l + ky) * 18;
            #pragma unroll
            for (int kx = 0; kx < 3; ++kx) {
                int cc = px_l + kx;
                bf16x8 bf = *(const bf16x8*)(xt + (((rowb + cc) << 2) + (kg ^ (cc & 3))) * 4);
                a0 = __builtin_amdgcn_mfma_f32_16x16x32_bf16(wf[ky * 3 + kx][0], bf, a0, 0, 0, 0);
                a1 = __builtin_amdgcn_mfma_f32_16x16x32_bf16(wf[ky * 3 + kx][1], bf, a1, 0, 0, 0);
            }
        }
        int py = ty0 + py_l, px = tx0 + px_l;
        size_t pbase = (size_t)py * 256 + px;
        {
            float y0 = a0[0] * dc[0][0] + bs[0][0];
            float y1 = a0[1] * dc[0][1] + bs[0][1];
            float y2 = a0[2] * dc[0][2] + bs[0][2];
            float y3 = a0[3] * dc[0][3] + bs[0][3];
            y0 = (y0 > 0.f ? y0 : 0.2f * y0) * 1.4142135623730951f;
            y1 = (y1 > 0.f ? y1 : 0.2f * y1) * 1.4142135623730951f;
            y2 = (y2 > 0.f ? y2 : 0.2f * y2) * 1.4142135623730951f;
            y3 = (y3 > 0.f ? y3 : 0.2f * y3) * 1.4142135623730951f;
            int lp0 = kg * 2;
            tokens[((size_t)(b * NL + lp0)) * NPIX + pbase] = packbf(y0, y1);
            tokens[((size_t)(b * NL + lp0 + 1)) * NPIX + pbase] = packbf(y2, y3);
        }
        {
            float y0 = a1[0] * dc[1][0] + bs[1][0];
            float y1 = a1[1] * dc[1][1] + bs[1][1];
            float y2 = a1[2] * dc[1][2] + bs[1][2];
            float y3 = a1[3] * dc[1][3] + bs[1][3];
            y0 = (y0 > 0.f ? y0 : 0.2f * y0) * 1.4142135623730951f;
            y1 = (y1 > 0.f ? y1 : 0.2f * y1) * 1.4142135623730951f;
            y2 = (y2 > 0.f ? y2 : 0.2f * y2) * 1.4142135623730951f;
            y3 = (y3 > 0.f ? y3 : 0.2f * y3) * 1.4142135623730951f;
            int lp0 = 8 + kg * 2;
            tokens[((size_t)(b * NL + lp0)) * NPIX + pbase] = packbf(y0, y1);
            tokens[((size_t)(b * NL + lp0 + 1)) * NPIX + pbase] = packbf(y2, y3);
        }
    }
}

// ---- K3a: recon stage 1, LDS-staged — block = (l, 4 rows); wave = one row ----
__global__ __launch_bounds__(256) void k_recon1(const uint32_t* __restrict__ tokens,
                                                const int* __restrict__ ctab,
                                                const float* __restrict__ ftab,
                                                const int* __restrict__ stab,
                                                uint32_t* __restrict__ U, LevelParams p) {
    __shared__ float2 cf[256];                 // (cell as int-bits, frac) per pixel col
    __shared__ int sl[260];                    // lower-bound table S[0..r]
    __shared__ uint32_t tok[4][256];           // 4 token rows (bf16x2)
    int l = blockIdx.x >> 6;
    int grp = blockIdx.x & 63;
    int b = blockIdx.y;
    int tid = threadIdx.x;
    int lane = tid & 63, wv = tid >> 6;
    int r = p.res[l];

    cf[tid] = make_float2(__int_as_float(ctab[l * 256 + tid]), ftab[l * 256 + tid]);
    for (int q = tid; q <= r; q += 256) sl[q] = stab[p.soff[l] + q];
    int i = grp * 4 + wv;
    const uint32_t* trow = tokens + (size_t)(b * NL + l) * NPIX + i * 256;
    *(uint4*)&tok[wv][lane * 4] = *(const uint4*)(trow + lane * 4);
    __syncthreads();

    uint32_t* Ul = U + (size_t)b * (p.sumr * 256) + p.uoff[l] + (size_t)i * r;
    int nck = p.nck[l];
    #pragma unroll 1
    for (int ck = 0; ck < nck; ++ck) {
        int cx = ck * 64 + lane;
        bool valid = cx < r;
        int jlo = 0, jhi = -1;
        if (valid) {
            jlo = (cx > 0) ? sl[cx - 1] : 0;
            jhi = sl[min(cx + 1, r)] - 1;
        }
        float a0 = 0.f, a1 = 0.f;
        for (int j = jlo; j <= jhi; ++j) {
            float2 cfv = cf[j];
            int c = __float_as_int(cfv.x);
            float f = cfv.y;
            float w = (c == cx) ? (1.f - f) : f;
            uint32_t tv = tok[wv][j];
            a0 += w * bflo(tv);
            a1 += w * bfhi(tv);
        }
        if (valid)
            Ul[cx] = packh2(a0, a1);
    }
}

// ---- K3b: recon stage 2 — wave per (level, cy, 64-wide cx chunk) ----
__global__ __launch_bounds__(256) void k_recon2(const uint32_t* __restrict__ U,
                                                const int* __restrict__ ctab,
                                                const float* __restrict__ ftab,
                                                const int* __restrict__ stab,
                                                float* __restrict__ R, LevelParams p) {
    int wid = blockIdx.x * 4 + (threadIdx.x >> 6);
    int lane = threadIdx.x & 63;
    int b = blockIdx.y;
    if (wid >= p.nwaves) return;
    int l = 0;
    #pragma unroll
    for (int q = 1; q < NL; ++q) if (wid >= p.cwoff[q]) l = q;
    int u = wid - p.cwoff[l];
    int r = p.res[l];
    int nck = p.nck[l];
    int cy = u / nck;
    int ck = u - cy * nck;
    int cx = ck * 64 + lane;
    bool valid = cx < r;
    const int* Sl = stab + p.soff[l];
    int ilo = (cy > 0) ? Sl[cy - 1] : 0;
    int ihi = Sl[min(cy + 1, r)] - 1;
    const uint32_t* Ub = U + (size_t)b * (p.sumr * 256) + p.uoff[l];
    const int* crow = ctab + l * 256;
    const float* frow = ftab + l * 256;
    float a0 = 0.f, a1 = 0.f;
    for (int i = ilo; i <= ihi; ++i) {
        int c = crow[i];
        float f = frow[i];
        float w = (c == cy) ? (1.f - f) : f;
        if (valid) {
            uint32_t uu = Ub[(size_t)i * r + cx];
            a0 += w * h2lo(uu);
            a1 += w * h2hi(uu);
        }
    }
    if (!valid) return;
    float* Rbl = R + (size_t)(b * NL + l) * TD * 2;
    if (p.hashed[l]) {
        uint32_t h = ((uint32_t)cx ^ ((uint32_t)cy * PRIME)) & (TD - 1);
        atomicAdd(&Rbl[2 * h], a0);
        atomicAdd(&Rbl[2 * h + 1], a1);
    } else {
        *(float2*)(Rbl + 2 * (cy * r + cx)) = make_float2(a0, a1);
    }
}

// ---- K4: residual + LayerNorm(16384) -> FP32 out ----
__global__ __launch_bounds__(512) void k_ln(const float* __restrict__ R,
                                            const float* __restrict__ inp,
                                            float* __restrict__ out) {
    int row = blockIdx.x;                       // b*NL + l
    const float4* rv = (const float4*)(R + (size_t)row * 16384);
    const float4* iv = (const float4*)(inp + (size_t)row * 16384);
    int tid = threadIdx.x;
    float sum = 0.f, ssq = 0.f;
    for (int k = tid; k < 4096; k += 512) {
        float4 a = rv[k], c = iv[k];
        float x0 = a.x + c.x, x1 = a.y + c.y, x2 = a.z + c.z, x3 = a.w + c.w;
        sum += x0 + x1 + x2 + x3;
        ssq += x0 * x0 + x1 * x1 + x2 * x2 + x3 * x3;
    }
    #pragma unroll
    for (int off = 32; off > 0; off >>= 1) {
        sum += __shfl_xor(sum, off, 64);
        ssq += __shfl_xor(ssq, off, 64);
    }
    __shared__ float red[16];
    int w = tid >> 6;
    if ((tid & 63) == 0) { red[w * 2] = sum; red[w * 2 + 1] = ssq; }
    __syncthreads();
    sum = 0.f; ssq = 0.f;
    #pragma unroll
    for (int q = 0; q < 8; ++q) { sum += red[q * 2]; ssq += red[q * 2 + 1]; }
    float mu = sum * (1.f / 16384.f);
    float var = ssq * (1.f / 16384.f) - mu * mu;
    float inv = rsqrtf(var + 1e-5f);
    float4* ob = (float4*)(out + (size_t)row * 16384);
    for (int k = tid; k < 4096; k += 512) {
        float4 a = rv[k], c = iv[k];
        float4 o4;
        o4.x = (a.x + c.x - mu) * inv;
        o4.y = (a.y + c.y - mu) * inv;
        o4.z = (a.z + c.z - mu) * inv;
        o4.w = (a.w + c.w - mu) * inv;
        ob[k] = o4;
    }
}

extern "C" void kernel_launch(void* const* d_in, const int* in_sizes, int n_in,
                              void* d_out, int out_size, void* d_ws, size_t ws_size,
                              hipStream_t stream) {
    const float* inputs = (const float*)d_in[0];
    const float* s      = (const float*)d_in[1];
    const float* coords = (const float*)d_in[2];
    const float* aw     = (const float*)d_in[3];
    const float* ab     = (const float*)d_in[4];
    const float* cw     = (const float*)d_in[5];
    const float* cb     = (const float*)d_in[6];

    char* ws = (char*)d_ws;
    uint32_t* U      = (uint32_t*)(ws);                 // 11.7 MB used (fp16x2 packed)
    uint32_t* ctileG = (uint32_t*)(ws + 16777216);      // 14.5 MB (dead part of U slot)
    uint32_t* tokens = (uint32_t*)(ws + 33554432);      // 33,554,432 B
    float*    R      = (float*)(ws + 67108864);         //  8,388,608 B
    float*    styles = (float*)(ws + 75497472);         // 1 KB
    float*    dcoef  = (float*)(ws + 75498496);         // 1 KB
    int*      ctab   = (int*)(ws + 75499520);           // 16 KB
    float*    ftab   = (float*)(ws + 75515904);         // 16 KB
    int*      stab   = (int*)(ws + 75532288);           // 8 KB
    unsigned short* wpack = (unsigned short*)(ws + 75540480); // 18.4 KB

    // RES_LIST exactly as numpy computes it (double libm ops).
    LevelParams p;
    double bb = exp((log(256.0) - log(16.0)) / 15.0);
    int uoff = 0, soff = 0, cwoff = 0, sumr = 0;
    for (int l = 0; l < NL; ++l) {
        int r = (int)floor(16.0 * pow(bb, (double)l));
        p.res[l] = r;
        p.hashed[l] = (r * r > TD) ? 1 : 0;
        p.uoff[l] = uoff;
        p.soff[l] = soff;
        p.cwoff[l] = cwoff;
        int nck = (r + 63) >> 6;
        p.nck[l] = nck;
        uoff += r * 256;
        soff += r + 2;
        cwoff += r * nck;
        sumr += r;
    }
    p.sumr = sumr;
    p.nwaves = cwoff;

    hipMemsetAsync(R, 0, (size_t)NB * NL * TD * 2 * sizeof(float), stream);
    hipLaunchKernelGGL(k_prep, dim3(NB + NL + 36), dim3(256), 0, stream,
                       s, aw, ab, cw, coords, styles, dcoef, ctab, ftab, stab, wpack, p);
    hipLaunchKernelGGL(k_gather, dim3(2048), dim3(256), 0, stream,
                       inputs, ctab, styles, ctileG, p);
    hipLaunchKernelGGL(k_conv, dim3(2048), dim3(256), 0, stream,
                       ctileG, ctab, ftab, wpack, cb, dcoef, tokens, p);
    hipLaunchKernelGGL(k_recon1, dim3(NL * 64, NB), dim3(256), 0, stream,
                       tokens, ctab, ftab, stab, U, p);
    hipLaunchKernelGGL(k_recon2, dim3((p.nwaves + 3) / 4, NB), dim3(256), 0, stream,
                       U, ctab, ftab, stab, R, p);
    hipLaunchKernelGGL(k_ln, dim3(NB * NL), dim3(512), 0, stream,
                       R, inputs, (float*)d_out);
}

// Round 20
// 103.278 us; speedup vs baseline: 1.5768x; 1.0661x over previous
//
#include <hip/hip_runtime.h>
#include <hip/hip_fp16.h>
#include <cmath>
#include <cstdint>

#define NB 8
#define NL 16
#define TD 8192
#define NPIX 65536
#define CH 32
#define SD 512

static constexpr uint32_t PRIME = 2654435761u;

typedef __attribute__((ext_vector_type(8))) short bf16x8;
typedef __attribute__((ext_vector_type(4))) float f32x4;

// per-level corner-tile capacities for a 16x16 tile (+halo, 17-px span)
static constexpr int cNCX[16] = {4,5,5,5,6,6,7,7,8,9,10,12,13,15,18,20};
static constexpr int CTOFF[17] = {0,16,41,66,91,127,163,212,261,325,406,506,650,819,1044,1368,1768};

struct LevelParams {
    int res[NL];
    int hashed[NL];
    int uoff[NL];    // prefix of 256*r u32 (per batch) into packed U [i][cx]
    int soff[NL];    // prefix of (r+2) ints into stab
    int cwoff[NL];   // recon2 wave prefix (r*nck)
    int nck[NL];     // ceil(r/64)
    int sumr;
    int nwaves;      // recon2 waves per batch
};

// ---- bf16 helpers (RNE) ----
__device__ __forceinline__ unsigned short f2bf(float f) {
    uint32_t u = __float_as_uint(f);
    return (unsigned short)((u + 0x7fffu + ((u >> 16) & 1u)) >> 16);
}
__device__ __forceinline__ float bflo(uint32_t u) { return __uint_as_float(u << 16); }
__device__ __forceinline__ float bfhi(uint32_t u) { return __uint_as_float(u & 0xffff0000u); }
__device__ __forceinline__ uint32_t packbf(float a, float b) {
    return (uint32_t)f2bf(a) | ((uint32_t)f2bf(b) << 16);
}
// ---- fp16x2 pack helpers for U ----
__device__ __forceinline__ uint32_t packh2(float a, float b) {
    return (uint32_t)__half_as_ushort(__float2half_rn(a)) |
           ((uint32_t)__half_as_ushort(__float2half_rn(b)) << 16);
}
__device__ __forceinline__ float h2lo(uint32_t u) {
    return __half2float(__ushort_as_half((unsigned short)(u & 0xffffu)));
}
__device__ __forceinline__ float h2hi(uint32_t u) {
    return __half2float(__ushort_as_half((unsigned short)(u >> 16)));
}

// ---- K_prep: styles+dcoef (0..7), wtab (8..23), wpack (24..59), R-zero (60..571) ----
__global__ __launch_bounds__(256) void k_prep(
    const float* __restrict__ s, const float* __restrict__ aw,
    const float* __restrict__ ab, const float* __restrict__ cw,
    const float* __restrict__ coords,
    float* __restrict__ styles, float* __restrict__ dcoef,
    int* __restrict__ ctab, float* __restrict__ ftab, int* __restrict__ stab,
    unsigned short* __restrict__ wpack, float* __restrict__ R, LevelParams p) {
    int bb = blockIdx.x;
    int t = threadIdx.x;
    if (bb < NB) {
        int b = bb;
        int c = t >> 3, part = t & 7;               // 32 ch x 8 parts
        const float* sv = s + b * SD + part * 64;
        const float* wv = aw + c * SD + part * 64;
        float acc = 0.f;
        #pragma unroll 8
        for (int k = 0; k < 64; ++k) acc += sv[k] * wv[k];
        acc += __shfl_xor(acc, 1, 64);
        acc += __shfl_xor(acc, 2, 64);
        acc += __shfl_xor(acc, 4, 64);
        __shared__ float st_sh[CH];
        if (part == 0) {
            float st = acc * 0.04419417382415922f /* 1/sqrt(512) */ + ab[c];
            styles[b * CH + c] = st;
            st_sh[c] = st;
        }
        __syncthreads();
        if (t < CH) {
            float d = 0.f;
            for (int i = 0; i < CH; ++i) {
                const float* w9 = cw + (t * CH + i) * 9;
                float ws = 0.f;
                #pragma unroll
                for (int k = 0; k < 9; ++k) ws += w9[k] * w9[k];
                float si = st_sh[i];
                d += ws * si * si;
            }
            dcoef[b * CH + t] = rsqrtf(d + 1e-8f);
        }
    } else if (bb < NB + NL) {
        int l = bb - NB;
        int j = t;
        int r = p.res[l];
        float g = coords[2 * j];                   // x-coord of col j == y-coord of row j
        float px = g * (float)(r - 1);
        float fl = floorf(px);
        float f = px - fl;
        int c = min((int)fl, r - 2);
        ctab[l * 256 + j] = c;
        ftab[l * 256 + j] = f;
        __shared__ int cs[256];
        cs[j] = c;
        __syncthreads();
        for (int cc = j; cc <= r; cc += 256) {
            int cnt = 0;
            for (int i = 0; i < 256; ++i) cnt += (cs[i] < cc) ? 1 : 0;
            stab[p.soff[l] + cc] = cnt;
        }
    } else if (bb < NB + NL + 36) {
        int idx = (bb - NB - NL) * 256 + t;
        if (idx < 9 * 4 * 32 * 8) {
            int j = idx & 7;
            int o = (idx >> 3) & 31;
            int kgi = (idx >> 8) & 3;
            int tap = idx >> 10;
            wpack[idx] = f2bf(cw[(o * 32 + kgi * 8 + j) * 9 + tap]);
        }
    } else {
        // zero-fill R: blocks 60..571, each 1024 uint4 (16 KB)
        float4* Rv = (float4*)R;
        int base = (bb - NB - NL - 36) * 1024;
        float4 z = make_float4(0.f, 0.f, 0.f, 0.f);
        #pragma unroll
        for (int q = 0; q < 4; ++q)
            Rv[base + q * 256 + t] = z;
    }
}

// ---- K_gather: pre-gather deduped premod corner tiles per (tile,batch) ----
__global__ __launch_bounds__(256) void k_gather(
    const float* __restrict__ tables, const int* __restrict__ ctab,
    const float* __restrict__ styles, uint32_t* __restrict__ ctileG,
    LevelParams p) {
    __shared__ int cxbase[NL], cybase[NL], ncxA[NL], ncyA[NL];
    int bid = blockIdx.x;                      // 2048
    int b = bid & 7;
    int t = bid >> 3;
    int tx0 = (t & 15) * 16, ty0 = (t >> 4) * 16;
    int tid = threadIdx.x;
    const float* tb = tables + (size_t)b * NL * TD * 2;
    if (tid < NL) {
        int l = tid;
        int cxb = ctab[l * 256 + max(tx0 - 1, 0)];
        int cyb = ctab[l * 256 + max(ty0 - 1, 0)];
        cxbase[l] = cxb;
        cybase[l] = cyb;
        ncxA[l] = ctab[l * 256 + min(tx0 + 16, 255)] - cxb + 2;
        ncyA[l] = ctab[l * 256 + min(ty0 + 16, 255)] - cyb + 2;
    }
    __syncthreads();
    uint32_t* out = ctileG + (size_t)bid * 1768;
    #pragma unroll
    for (int l = 0; l < NL; ++l) {
        const int NCXl = cNCX[l];
        const int CAP = (CTOFF[l + 1] - CTOFF[l]);
        float s0 = styles[b * CH + 2 * l], s1 = styles[b * CH + 2 * l + 1];
        for (int u2 = tid; u2 < CAP; u2 += 256) {
            int sy = u2 / NCXl;
            int sx = u2 - sy * NCXl;
            uint32_t val = 0u;
            if (sx < ncxA[l] && sy < ncyA[l]) {
                int ax = cxbase[l] + sx, ay = cybase[l] + sy;
                int r = p.res[l];
                uint32_t idx = p.hashed[l]
                    ? (((uint32_t)ax ^ ((uint32_t)ay * PRIME)) & (TD - 1))
                    : (uint32_t)(ay * r + ax);
                float2 g = *(const float2*)(tb + (size_t)l * TD * 2 + 2 * idx);
                val = packbf(g.x * s0, g.y * s1);
            }
            out[CTOFF[l] + u2] = val;          // coalesced
        }
    }
}

// ---- fused retrieve feature from (cell-rel,frac) + LDS corners ----
template<int L>
__device__ __forceinline__ uint32_t feat1p(float2 cv, float2 rv, const uint32_t* ctile) {
    int a = CTOFF[L] + __float_as_int(rv.x) * cNCX[L] + __float_as_int(cv.x);
    float fx = cv.y, fy = rv.y;
    uint32_t c00 = ctile[a], c10 = ctile[a + 1];             // ds_read2_b32
    uint32_t c01 = ctile[a + cNCX[L]], c11 = ctile[a + cNCX[L] + 1];
    float w00 = (1.f - fx) * (1.f - fy), w10 = fx * (1.f - fy);
    float w01 = (1.f - fx) * fy,         w11 = fx * fy;
    float f0 = w00 * bflo(c00) + w10 * bflo(c10) + w01 * bflo(c01) + w11 * bflo(c11);
    float f1 = w00 * bfhi(c00) + w10 * bfhi(c10) + w01 * bfhi(c01) + w11 * bfhi(c11);
    return packbf(f0, f1);
}

// ---- phase 1: one wave = 4 levels, all 324 halo px ----
template<int L0>
__device__ __forceinline__ void phase1(int lane, int tx0, int ty0,
                                       const float2* col2, const float2* row2,
                                       const uint32_t* ctile, uint32_t* xt) {
    constexpr int q = L0 / 4;
    #pragma unroll
    for (int it = 0; it < 6; ++it) {
        int pl = it * 64 + lane;
        int rr = pl / 18, cc = pl - rr * 18;
        int gy = ty0 + rr - 1, gx = tx0 + cc - 1;
        uint4 v = make_uint4(0u, 0u, 0u, 0u);
        if (pl < 324 && (unsigned)gy < 256u && (unsigned)gx < 256u) {
            float2 cv0 = col2[(L0 + 0) * 18 + cc], rv0 = row2[(L0 + 0) * 18 + rr];
            float2 cv1 = col2[(L0 + 1) * 18 + cc], rv1 = row2[(L0 + 1) * 18 + rr];
            float2 cv2 = col2[(L0 + 2) * 18 + cc], rv2 = row2[(L0 + 2) * 18 + rr];
            float2 cv3 = col2[(L0 + 3) * 18 + cc], rv3 = row2[(L0 + 3) * 18 + rr];
            v.x = feat1p<L0 + 0>(cv0, rv0, ctile);
            v.y = feat1p<L0 + 1>(cv1, rv1, ctile);
            v.z = feat1p<L0 + 2>(cv2, rv2, ctile);
            v.w = feat1p<L0 + 3>(cv3, rv3, ctile);
        }
        if (pl < 324)
            *(uint4*)(xt + (size_t)(pl * 4 + (q ^ (cc & 3))) * 4) = v;
    }
}

// ---- K2: FUSED retrieve+mod+MFMA 3x3 conv; corners pre-gathered ----
__global__ __launch_bounds__(256) void k_conv(
    const uint32_t* __restrict__ ctileG, const int* __restrict__ ctab,
    const float* __restrict__ ftab,
    const unsigned short* __restrict__ wpack, const float* __restrict__ cb,
    const float* __restrict__ dcoef, uint32_t* __restrict__ tokens,
    LevelParams p) {
    __shared__ uint32_t xt[18 * 18 * 16];      // 20736 B feature tile (bf16x2 chunks)
    __shared__ uint32_t ctile[1768];           // 7072 B premod corners (bf16x2)
    __shared__ float2 col2[NL * 18];           // 2304 B (cell-rel, frac) per halo col
    __shared__ float2 row2[NL * 18];           // 2304 B per halo row
    __shared__ int cxbase[NL], cybase[NL];

    int bid = blockIdx.x;
    int b = bid & 7;
    int t = bid >> 3;
    int tx0 = (t & 15) * 16, ty0 = (t >> 4) * 16;
    int tid = threadIdx.x;
    int lane = tid & 63, wv = tid >> 6;        // 4 waves
    int npx = lane & 15, kg = lane >> 4;

    // ---- setup: extents + coalesced ctile load + col2/row2 ----
    if (tid < NL) {
        int l = tid;
        cxbase[l] = ctab[l * 256 + max(tx0 - 1, 0)];
        cybase[l] = ctab[l * 256 + max(ty0 - 1, 0)];
    }
    {
        const uint4* src = (const uint4*)(ctileG + (size_t)bid * 1768);
        for (int i = tid; i < 442; i += 256)
            *(uint4*)(ctile + i * 4) = src[i];
    }
    __syncthreads();
    for (int u0 = tid; u0 < NL * 36; u0 += 256) {
        int l = u0 / 36, pos = u0 - l * 36;
        if (pos < 18) {
            int gx = tx0 - 1 + pos;
            int gxc = min(max(gx, 0), 255);
            col2[l * 18 + pos] = make_float2(
                __int_as_float(ctab[l * 256 + gxc] - cxbase[l]), ftab[l * 256 + gxc]);
        } else {
            int pr = pos - 18;
            int gy = ty0 - 1 + pr;
            int gyc = min(max(gy, 0), 255);
            row2[l * 18 + pr] = make_float2(
                __int_as_float(ctab[l * 256 + gyc] - cybase[l]), ftab[l * 256 + gyc]);
        }
    }
    __syncthreads();

    // ---- phase 1: wave-uniform 4-level feature computation -> xt (all-LDS) ----
    switch (wv) {
        case 0: phase1<0>(lane, tx0, ty0, col2, row2, ctile, xt); break;
        case 1: phase1<4>(lane, tx0, ty0, col2, row2, ctile, xt); break;
        case 2: phase1<8>(lane, tx0, ty0, col2, row2, ctile, xt); break;
        default: phase1<12>(lane, tx0, ty0, col2, row2, ctile, xt); break;
    }
    __builtin_amdgcn_sched_barrier(0);         // keep wf loads out of phase-1 live range

    // ---- weights (prepacked bf16 fragments) + demod/bias ----
    bf16x8 wf[9][2];
    #pragma unroll
    for (int tp = 0; tp < 9; ++tp) {
        wf[tp][0] = *(const bf16x8*)(wpack + (size_t)((tp * 4 + kg) * 32 + npx) * 8);
        wf[tp][1] = *(const bf16x8*)(wpack + (size_t)((tp * 4 + kg) * 32 + 16 + npx) * 8);
    }
    float dc[2][4], bs[2][4];
    #pragma unroll
    for (int ob = 0; ob < 2; ++ob)
        #pragma unroll
        for (int rg = 0; rg < 4; ++rg) {
            int oc = ob * 16 + kg * 4 + rg;
            dc[ob][rg] = dcoef[b * CH + oc];
            bs[ob][rg] = cb[oc];
        }
    __syncthreads();

    // ---- phase 2: MFMA conv (4 iterations per wave; group = one 16-px row) ----
    #pragma unroll 1
    for (int it = 0; it < 4; ++it) {
        int py_l = it * 4 + wv;                // 16 rows
        int px_l = npx;
        f32x4 a0 = {0.f, 0.f, 0.f, 0.f};
        f32x4 a1 = {0.f, 0.f, 0.f, 0.f};
        #pragma unroll
        for (int ky = 0; ky < 3; ++ky) {
            int rowb = (py_l + ky) * 18;
            #pragma unroll
            for (int kx = 0; kx < 3; ++kx) {
                int cc = px_l + kx;
                bf16x8 bf = *(const bf16x8*)(xt + (((rowb + cc) << 2) + (kg ^ (cc & 3))) * 4);
                a0 = __builtin_amdgcn_mfma_f32_16x16x32_bf16(wf[ky * 3 + kx][0], bf, a0, 0, 0, 0);
                a1 = __builtin_amdgcn_mfma_f32_16x16x32_bf16(wf[ky * 3 + kx][1], bf, a1, 0, 0, 0);
            }
        }
        int py = ty0 + py_l, px = tx0 + px_l;
        size_t pbase = (size_t)py * 256 + px;
        {
            float y0 = a0[0] * dc[0][0] + bs[0][0];
            float y1 = a0[1] * dc[0][1] + bs[0][1];
            float y2 = a0[2] * dc[0][2] + bs[0][2];
            float y3 = a0[3] * dc[0][3] + bs[0][3];
            y0 = (y0 > 0.f ? y0 : 0.2f * y0) * 1.4142135623730951f;
            y1 = (y1 > 0.f ? y1 : 0.2f * y1) * 1.4142135623730951f;
            y2 = (y2 > 0.f ? y2 : 0.2f * y2) * 1.4142135623730951f;
            y3 = (y3 > 0.f ? y3 : 0.2f * y3) * 1.4142135623730951f;
            int lp0 = kg * 2;
            tokens[((size_t)(b * NL + lp0)) * NPIX + pbase] = packbf(y0, y1);
            tokens[((size_t)(b * NL + lp0 + 1)) * NPIX + pbase] = packbf(y2, y3);
        }
        {
            float y0 = a1[0] * dc[1][0] + bs[1][0];
            float y1 = a1[1] * dc[1][1] + bs[1][1];
            float y2 = a1[2] * dc[1][2] + bs[1][2];
            float y3 = a1[3] * dc[1][3] + bs[1][3];
            y0 = (y0 > 0.f ? y0 : 0.2f * y0) * 1.4142135623730951f;
            y1 = (y1 > 0.f ? y1 : 0.2f * y1) * 1.4142135623730951f;
            y2 = (y2 > 0.f ? y2 : 0.2f * y2) * 1.4142135623730951f;
            y3 = (y3 > 0.f ? y3 : 0.2f * y3) * 1.4142135623730951f;
            int lp0 = 8 + kg * 2;
            tokens[((size_t)(b * NL + lp0)) * NPIX + pbase] = packbf(y0, y1);
            tokens[((size_t)(b * NL + lp0 + 1)) * NPIX + pbase] = packbf(y2, y3);
        }
    }
}

// ---- K3a: recon stage 1, LDS-staged — block = (l, 8 rows); wave = 2 rows ----
// U[b][l][i][cx] (fp16x2) = sum_j w(j,cx) * T[i][j]; (jlo,jhi,w) shared by row pair
__global__ __launch_bounds__(256) void k_recon1(const uint32_t* __restrict__ tokens,
                                                const int* __restrict__ ctab,
                                                const float* __restrict__ ftab,
                                                const int* __restrict__ stab,
                                                uint32_t* __restrict__ U, LevelParams p) {
    __shared__ float2 cf[256];                 // (cell as int-bits, frac) per pixel col
    __shared__ int sl[260];                    // lower-bound table S[0..r]
    __shared__ uint32_t tok[8][256];           // 8 token rows (bf16x2)
    int l = blockIdx.x >> 5;
    int grp = blockIdx.x & 31;
    int b = blockIdx.y;
    int tid = threadIdx.x;
    int lane = tid & 63, wv = tid >> 6;
    int r = p.res[l];

    cf[tid] = make_float2(__int_as_float(ctab[l * 256 + tid]), ftab[l * 256 + tid]);
    for (int q = tid; q <= r; q += 256) sl[q] = stab[p.soff[l] + q];
    int i0 = grp * 8 + wv * 2;                 // first of this wave's 2 rows
    const uint32_t* trow = tokens + (size_t)(b * NL + l) * NPIX + i0 * 256;
    *(uint4*)&tok[wv * 2 + 0][lane * 4] = *(const uint4*)(trow + lane * 4);
    *(uint4*)&tok[wv * 2 + 1][lane * 4] = *(const uint4*)(trow + 256 + lane * 4);
    __syncthreads();

    uint32_t* Ul0 = U + (size_t)b * (p.sumr * 256) + p.uoff[l] + (size_t)i0 * r;
    uint32_t* Ul1 = Ul0 + r;
    int nck = p.nck[l];
    #pragma unroll 1
    for (int ck = 0; ck < nck; ++ck) {
        int cx = ck * 64 + lane;
        bool valid = cx < r;
        int jlo = 0, jhi = -1;
        if (valid) {
            jlo = (cx > 0) ? sl[cx - 1] : 0;
            jhi = sl[min(cx + 1, r)] - 1;
        }
        float a00 = 0.f, a01 = 0.f, a10 = 0.f, a11 = 0.f;
        for (int j = jlo; j <= jhi; ++j) {
            float2 cfv = cf[j];
            int c = __float_as_int(cfv.x);
            float f = cfv.y;
            float w = (c == cx) ? (1.f - f) : f;
            uint32_t tv0 = tok[wv * 2 + 0][j];
            uint32_t tv1 = tok[wv * 2 + 1][j];
            a00 += w * bflo(tv0);
            a01 += w * bfhi(tv0);
            a10 += w * bflo(tv1);
            a11 += w * bfhi(tv1);
        }
        if (valid) {
            Ul0[cx] = packh2(a00, a01);
            Ul1[cx] = packh2(a10, a11);
        }
    }
}

// ---- K3b: recon stage 2 — wave per (level, cy, 64-wide cx chunk) ----
__global__ __launch_bounds__(256) void k_recon2(const uint32_t* __restrict__ U,
                                                const int* __restrict__ ctab,
                                                const float* __restrict__ ftab,
                                                const int* __restrict__ stab,
                                                float* __restrict__ R, LevelParams p) {
    int wid = blockIdx.x * 4 + (threadIdx.x >> 6);
    int lane = threadIdx.x & 63;
    int b = blockIdx.y;
    if (wid >= p.nwaves) return;
    int l = 0;
    #pragma unroll
    for (int q = 1; q < NL; ++q) if (wid >= p.cwoff[q]) l = q;
    int u = wid - p.cwoff[l];
    int r = p.res[l];
    int nck = p.nck[l];
    int cy = u / nck;
    int ck = u - cy * nck;
    int cx = ck * 64 + lane;
    bool valid = cx < r;
    const int* Sl = stab + p.soff[l];
    int ilo = (cy > 0) ? Sl[cy - 1] : 0;
    int ihi = Sl[min(cy + 1, r)] - 1;
    const uint32_t* Ub = U + (size_t)b * (p.sumr * 256) + p.uoff[l];
    const int* crow = ctab + l * 256;
    const float* frow = ftab + l * 256;
    float a0 = 0.f, a1 = 0.f;
    for (int i = ilo; i <= ihi; ++i) {
        int c = crow[i];
        float f = frow[i];
        float w = (c == cy) ? (1.f - f) : f;
        if (valid) {
            uint32_t uu = Ub[(size_t)i * r + cx];
            a0 += w * h2lo(uu);
            a1 += w * h2hi(uu);
        }
    }
    if (!valid) return;
    float* Rbl = R + (size_t)(b * NL + l) * TD * 2;
    if (p.hashed[l]) {
        uint32_t h = ((uint32_t)cx ^ ((uint32_t)cy * PRIME)) & (TD - 1);
        atomicAdd(&Rbl[2 * h], a0);
        atomicAdd(&Rbl[2 * h + 1], a1);
    } else {
        *(float2*)(Rbl + 2 * (cy * r + cx)) = make_float2(a0, a1);
    }
}

// ---- K4: residual + LayerNorm(16384) -> FP32 out ----
__global__ __launch_bounds__(512) void k_ln(const float* __restrict__ R,
                                            const float* __restrict__ inp,
                                            float* __restrict__ out) {
    int row = blockIdx.x;                       // b*NL + l
    const float4* rv = (const float4*)(R + (size_t)row * 16384);
    const float4* iv = (const float4*)(inp + (size_t)row * 16384);
    int tid = threadIdx.x;
    float sum = 0.f, ssq = 0.f;
    for (int k = tid; k < 4096; k += 512) {
        float4 a = rv[k], c = iv[k];
        float x0 = a.x + c.x, x1 = a.y + c.y, x2 = a.z + c.z, x3 = a.w + c.w;
        sum += x0 + x1 + x2 + x3;
        ssq += x0 * x0 + x1 * x1 + x2 * x2 + x3 * x3;
    }
    #pragma unroll
    for (int off = 32; off > 0; off >>= 1) {
        sum += __shfl_xor(sum, off, 64);
        ssq += __shfl_xor(ssq, off, 64);
    }
    __shared__ float red[16];
    int w = tid >> 6;
    if ((tid & 63) == 0) { red[w * 2] = sum; red[w * 2 + 1] = ssq; }
    __syncthreads();
    sum = 0.f; ssq = 0.f;
    #pragma unroll
    for (int q = 0; q < 8; ++q) { sum += red[q * 2]; ssq += red[q * 2 + 1]; }
    float mu = sum * (1.f / 16384.f);
    float var = ssq * (1.f / 16384.f) - mu * mu;
    float inv = rsqrtf(var + 1e-5f);
    float4* ob = (float4*)(out + (size_t)row * 16384);
    for (int k = tid; k < 4096; k += 512) {
        float4 a = rv[k], c = iv[k];
        float4 o4;
        o4.x = (a.x + c.x - mu) * inv;
        o4.y = (a.y + c.y - mu) * inv;
        o4.z = (a.z + c.z - mu) * inv;
        o4.w = (a.w + c.w - mu) * inv;
        ob[k] = o4;
    }
}

extern "C" void kernel_launch(void* const* d_in, const int* in_sizes, int n_in,
                              void* d_out, int out_size, void* d_ws, size_t ws_size,
                              hipStream_t stream) {
    const float* inputs = (const float*)d_in[0];
    const float* s      = (const float*)d_in[1];
    const float* coords = (const float*)d_in[2];
    const float* aw     = (const float*)d_in[3];
    const float* ab     = (const float*)d_in[4];
    const float* cw     = (const float*)d_in[5];
    const float* cb     = (const float*)d_in[6];

    char* ws = (char*)d_ws;
    uint32_t* U      = (uint32_t*)(ws);                 // 11.7 MB used (fp16x2 packed)
    uint32_t* ctileG = (uint32_t*)(ws + 16777216);      // 14.5 MB (dead part of U slot)
    uint32_t* tokens = (uint32_t*)(ws + 33554432);      // 33,554,432 B
    float*    R      = (float*)(ws + 67108864);         //  8,388,608 B
    float*    styles = (float*)(ws + 75497472);         // 1 KB
    float*    dcoef  = (float*)(ws + 75498496);         // 1 KB
    int*      ctab   = (int*)(ws + 75499520);           // 16 KB
    float*    ftab   = (float*)(ws + 75515904);         // 16 KB
    int*      stab   = (int*)(ws + 75532288);           // 8 KB
    unsigned short* wpack = (unsigned short*)(ws + 75540480); // 18.4 KB

    // RES_LIST exactly as numpy computes it (double libm ops).
    LevelParams p;
    double bb = exp((log(256.0) - log(16.0)) / 15.0);
    int uoff = 0, soff = 0, cwoff = 0, sumr = 0;
    for (int l = 0; l < NL; ++l) {
        int r = (int)floor(16.0 * pow(bb, (double)l));
        p.res[l] = r;
        p.hashed[l] = (r * r > TD) ? 1 : 0;
        p.uoff[l] = uoff;
        p.soff[l] = soff;
        p.cwoff[l] = cwoff;
        int nck = (r + 63) >> 6;
        p.nck[l] = nck;
        uoff += r * 256;
        soff += r + 2;
        cwoff += r * nck;
        sumr += r;
    }
    p.sumr = sumr;
    p.nwaves = cwoff;

    hipLaunchKernelGGL(k_prep, dim3(NB + NL + 36 + 512), dim3(256), 0, stream,
                       s, aw, ab, cw, coords, styles, dcoef, ctab, ftab, stab, wpack, R, p);
    hipLaunchKernelGGL(k_gather, dim3(2048), dim3(256), 0, stream,
                       inputs, ctab, styles, ctileG, p);
    hipLaunchKernelGGL(k_conv, dim3(2048), dim3(256), 0, stream,
                       ctileG, ctab, ftab, wpack, cb, dcoef, tokens, p);
    hipLaunchKernelGGL(k_recon1, dim3(NL * 32, NB), dim3(256), 0, stream,
                       tokens, ctab, ftab, stab, U, p);
    hipLaunchKernelGGL(k_recon2, dim3((p.nwaves + 3) / 4, NB), dim3(256), 0, stream,
                       U, ctab, ftab, stab, R, p);
    hipLaunchKernelGGL(k_ln, dim3(NB * NL), dim3(512), 0, stream,
                       R, inputs, (float*)d_out);
}

// Round 21
// 98.657 us; speedup vs baseline: 1.6507x; 1.0468x over previous
//
#include <hip/hip_runtime.h>
#include <hip/hip_fp16.h>
#include <cmath>
#include <cstdint>

#define NB 8
#define NL 16
#define TD 8192
#define NPIX 65536
#define CH 32
#define SD 512

static constexpr uint32_t PRIME = 2654435761u;

typedef __attribute__((ext_vector_type(8))) short bf16x8;
typedef __attribute__((ext_vector_type(4))) float f32x4;

// per-level corner-tile capacities for a 16x16 tile (+halo, 17-px span)
static constexpr int cNCX[16] = {4,5,5,5,6,6,7,7,8,9,10,12,13,15,18,20};
static constexpr int CTOFF[17] = {0,16,41,66,91,127,163,212,261,325,406,506,650,819,1044,1368,1768};

struct LevelParams {
    int res[NL];
    int hashed[NL];
    int uoff[NL];    // prefix of 256*r u32 (per batch) into packed U [i][cx]
    int soff[NL];    // prefix of (r+2) ints into stab
    int cwoff[NL];   // recon2 wave prefix (r*nck)
    int nck[NL];     // ceil(r/64)
    int sumr;
    int nwaves;      // recon2 waves per batch
};

// ---- bf16 helpers (RNE) ----
__device__ __forceinline__ unsigned short f2bf(float f) {
    uint32_t u = __float_as_uint(f);
    return (unsigned short)((u + 0x7fffu + ((u >> 16) & 1u)) >> 16);
}
__device__ __forceinline__ float bflo(uint32_t u) { return __uint_as_float(u << 16); }
__device__ __forceinline__ float bfhi(uint32_t u) { return __uint_as_float(u & 0xffff0000u); }
__device__ __forceinline__ uint32_t packbf(float a, float b) {
    return (uint32_t)f2bf(a) | ((uint32_t)f2bf(b) << 16);
}
// ---- fp16x2 pack helpers for U ----
__device__ __forceinline__ uint32_t packh2(float a, float b) {
    return (uint32_t)__half_as_ushort(__float2half_rn(a)) |
           ((uint32_t)__half_as_ushort(__float2half_rn(b)) << 16);
}
__device__ __forceinline__ float h2lo(uint32_t u) {
    return __half2float(__ushort_as_half((unsigned short)(u & 0xffffu)));
}
__device__ __forceinline__ float h2hi(uint32_t u) {
    return __half2float(__ushort_as_half((unsigned short)(u >> 16)));
}

// ---- K_prep: styles+dcoef (0..7), wtab (8..23), wpack (24..59), R-zero (60..571) ----
__global__ __launch_bounds__(256) void k_prep(
    const float* __restrict__ s, const float* __restrict__ aw,
    const float* __restrict__ ab, const float* __restrict__ cw,
    const float* __restrict__ coords,
    float* __restrict__ styles, float* __restrict__ dcoef,
    int* __restrict__ ctab, float* __restrict__ ftab, int* __restrict__ stab,
    unsigned short* __restrict__ wpack, float* __restrict__ R, LevelParams p) {
    int bb = blockIdx.x;
    int t = threadIdx.x;
    if (bb < NB) {
        int b = bb;
        int c = t >> 3, part = t & 7;               // 32 ch x 8 parts
        const float* sv = s + b * SD + part * 64;
        const float* wv = aw + c * SD + part * 64;
        float acc = 0.f;
        #pragma unroll 8
        for (int k = 0; k < 64; ++k) acc += sv[k] * wv[k];
        acc += __shfl_xor(acc, 1, 64);
        acc += __shfl_xor(acc, 2, 64);
        acc += __shfl_xor(acc, 4, 64);
        __shared__ float st_sh[CH];
        if (part == 0) {
            float st = acc * 0.04419417382415922f /* 1/sqrt(512) */ + ab[c];
            styles[b * CH + c] = st;
            st_sh[c] = st;
        }
        __syncthreads();
        if (t < CH) {
            float d = 0.f;
            for (int i = 0; i < CH; ++i) {
                const float* w9 = cw + (t * CH + i) * 9;
                float ws = 0.f;
                #pragma unroll
                for (int k = 0; k < 9; ++k) ws += w9[k] * w9[k];
                float si = st_sh[i];
                d += ws * si * si;
            }
            dcoef[b * CH + t] = rsqrtf(d + 1e-8f);
        }
    } else if (bb < NB + NL) {
        int l = bb - NB;
        int j = t;
        int r = p.res[l];
        float g = coords[2 * j];                   // x-coord of col j == y-coord of row j
        float px = g * (float)(r - 1);
        float fl = floorf(px);
        float f = px - fl;
        int c = min((int)fl, r - 2);
        ctab[l * 256 + j] = c;
        ftab[l * 256 + j] = f;
        __shared__ int cs[256];
        cs[j] = c;
        __syncthreads();
        for (int cc = j; cc <= r; cc += 256) {
            int cnt = 0;
            for (int i = 0; i < 256; ++i) cnt += (cs[i] < cc) ? 1 : 0;
            stab[p.soff[l] + cc] = cnt;
        }
    } else if (bb < NB + NL + 36) {
        int idx = (bb - NB - NL) * 256 + t;
        if (idx < 9 * 4 * 32 * 8) {
            int j = idx & 7;
            int o = (idx >> 3) & 31;
            int kgi = (idx >> 8) & 3;
            int tap = idx >> 10;
            wpack[idx] = f2bf(cw[(o * 32 + kgi * 8 + j) * 9 + tap]);
        }
    } else {
        // zero-fill R: blocks 60..571, each 1024 uint4 (16 KB)
        float4* Rv = (float4*)R;
        int base = (bb - NB - NL - 36) * 1024;
        float4 z = make_float4(0.f, 0.f, 0.f, 0.f);
        #pragma unroll
        for (int q = 0; q < 4; ++q)
            Rv[base + q * 256 + t] = z;
    }
}

// ---- K_gather: pre-gather deduped premod corner tiles per (tile,batch) ----
__global__ __launch_bounds__(256) void k_gather(
    const float* __restrict__ tables, const int* __restrict__ ctab,
    const float* __restrict__ styles, uint32_t* __restrict__ ctileG,
    LevelParams p) {
    __shared__ int cxbase[NL], cybase[NL], ncxA[NL], ncyA[NL];
    int bid = blockIdx.x;                      // 2048
    int b = bid & 7;
    int t = bid >> 3;
    int tx0 = (t & 15) * 16, ty0 = (t >> 4) * 16;
    int tid = threadIdx.x;
    const float* tb = tables + (size_t)b * NL * TD * 2;
    if (tid < NL) {
        int l = tid;
        int cxb = ctab[l * 256 + max(tx0 - 1, 0)];
        int cyb = ctab[l * 256 + max(ty0 - 1, 0)];
        cxbase[l] = cxb;
        cybase[l] = cyb;
        ncxA[l] = ctab[l * 256 + min(tx0 + 16, 255)] - cxb + 2;
        ncyA[l] = ctab[l * 256 + min(ty0 + 16, 255)] - cyb + 2;
    }
    __syncthreads();
    uint32_t* out = ctileG + (size_t)bid * 1768;
    #pragma unroll
    for (int l = 0; l < NL; ++l) {
        const int NCXl = cNCX[l];
        const int CAP = (CTOFF[l + 1] - CTOFF[l]);
        float s0 = styles[b * CH + 2 * l], s1 = styles[b * CH + 2 * l + 1];
        for (int u2 = tid; u2 < CAP; u2 += 256) {
            int sy = u2 / NCXl;
            int sx = u2 - sy * NCXl;
            uint32_t val = 0u;
            if (sx < ncxA[l] && sy < ncyA[l]) {
                int ax = cxbase[l] + sx, ay = cybase[l] + sy;
                int r = p.res[l];
                uint32_t idx = p.hashed[l]
                    ? (((uint32_t)ax ^ ((uint32_t)ay * PRIME)) & (TD - 1))
                    : (uint32_t)(ay * r + ax);
                float2 g = *(const float2*)(tb + (size_t)l * TD * 2 + 2 * idx);
                val = packbf(g.x * s0, g.y * s1);
            }
            out[CTOFF[l] + u2] = val;          // coalesced
        }
    }
}

// ---- fused retrieve feature from (cell-rel,frac) + LDS corners ----
template<int L>
__device__ __forceinline__ uint32_t feat1p(float2 cv, float2 rv, const uint32_t* ctile) {
    int a = CTOFF[L] + __float_as_int(rv.x) * cNCX[L] + __float_as_int(cv.x);
    float fx = cv.y, fy = rv.y;
    uint32_t c00 = ctile[a], c10 = ctile[a + 1];             // ds_read2_b32
    uint32_t c01 = ctile[a + cNCX[L]], c11 = ctile[a + cNCX[L] + 1];
    float w00 = (1.f - fx) * (1.f - fy), w10 = fx * (1.f - fy);
    float w01 = (1.f - fx) * fy,         w11 = fx * fy;
    float f0 = w00 * bflo(c00) + w10 * bflo(c10) + w01 * bflo(c01) + w11 * bflo(c11);
    float f1 = w00 * bfhi(c00) + w10 * bfhi(c10) + w01 * bfhi(c01) + w11 * bfhi(c11);
    return packbf(f0, f1);
}

// ---- phase 1: one wave = 4 levels, all 324 halo px ----
template<int L0>
__device__ __forceinline__ void phase1(int lane, int tx0, int ty0,
                                       const float2* col2, const float2* row2,
                                       const uint32_t* ctile, uint32_t* xt) {
    constexpr int q = L0 / 4;
    #pragma unroll
    for (int it = 0; it < 6; ++it) {
        int pl = it * 64 + lane;
        int rr = pl / 18, cc = pl - rr * 18;
        int gy = ty0 + rr - 1, gx = tx0 + cc - 1;
        uint4 v = make_uint4(0u, 0u, 0u, 0u);
        if (pl < 324 && (unsigned)gy < 256u && (unsigned)gx < 256u) {
            float2 cv0 = col2[(L0 + 0) * 18 + cc], rv0 = row2[(L0 + 0) * 18 + rr];
            float2 cv1 = col2[(L0 + 1) * 18 + cc], rv1 = row2[(L0 + 1) * 18 + rr];
            float2 cv2 = col2[(L0 + 2) * 18 + cc], rv2 = row2[(L0 + 2) * 18 + rr];
            float2 cv3 = col2[(L0 + 3) * 18 + cc], rv3 = row2[(L0 + 3) * 18 + rr];
            v.x = feat1p<L0 + 0>(cv0, rv0, ctile);
            v.y = feat1p<L0 + 1>(cv1, rv1, ctile);
            v.z = feat1p<L0 + 2>(cv2, rv2, ctile);
            v.w = feat1p<L0 + 3>(cv3, rv3, ctile);
        }
        if (pl < 324)
            *(uint4*)(xt + (size_t)(pl * 4 + (q ^ (cc & 3))) * 4) = v;
    }
}

// ---- K2: FUSED retrieve+mod+MFMA 3x3 conv; corners pre-gathered ----
__global__ __launch_bounds__(256) void k_conv(
    const uint32_t* __restrict__ ctileG, const int* __restrict__ ctab,
    const float* __restrict__ ftab,
    const unsigned short* __restrict__ wpack, const float* __restrict__ cb,
    const float* __restrict__ dcoef, uint32_t* __restrict__ tokens,
    LevelParams p) {
    __shared__ uint32_t xt[18 * 18 * 16];      // 20736 B feature tile (bf16x2 chunks)
    __shared__ uint32_t ctile[1768];           // 7072 B premod corners (bf16x2)
    __shared__ float2 col2[NL * 18];           // 2304 B (cell-rel, frac) per halo col
    __shared__ float2 row2[NL * 18];           // 2304 B per halo row
    __shared__ int cxbase[NL], cybase[NL];

    int bid = blockIdx.x;
    int b = bid & 7;
    int t = bid >> 3;
    int tx0 = (t & 15) * 16, ty0 = (t >> 4) * 16;
    int tid = threadIdx.x;
    int lane = tid & 63, wv = tid >> 6;        // 4 waves
    int npx = lane & 15, kg = lane >> 4;

    // ---- setup: extents + coalesced ctile load + col2/row2 ----
    if (tid < NL) {
        int l = tid;
        cxbase[l] = ctab[l * 256 + max(tx0 - 1, 0)];
        cybase[l] = ctab[l * 256 + max(ty0 - 1, 0)];
    }
    {
        const uint4* src = (const uint4*)(ctileG + (size_t)bid * 1768);
        for (int i = tid; i < 442; i += 256)
            *(uint4*)(ctile + i * 4) = src[i];
    }
    __syncthreads();
    for (int u0 = tid; u0 < NL * 36; u0 += 256) {
        int l = u0 / 36, pos = u0 - l * 36;
        if (pos < 18) {
            int gx = tx0 - 1 + pos;
            int gxc = min(max(gx, 0), 255);
            col2[l * 18 + pos] = make_float2(
                __int_as_float(ctab[l * 256 + gxc] - cxbase[l]), ftab[l * 256 + gxc]);
        } else {
            int pr = pos - 18;
            int gy = ty0 - 1 + pr;
            int gyc = min(max(gy, 0), 255);
            row2[l * 18 + pr] = make_float2(
                __int_as_float(ctab[l * 256 + gyc] - cybase[l]), ftab[l * 256 + gyc]);
        }
    }
    __syncthreads();

    // ---- phase 1: wave-uniform 4-level feature computation -> xt (all-LDS) ----
    switch (wv) {
        case 0: phase1<0>(lane, tx0, ty0, col2, row2, ctile, xt); break;
        case 1: phase1<4>(lane, tx0, ty0, col2, row2, ctile, xt); break;
        case 2: phase1<8>(lane, tx0, ty0, col2, row2, ctile, xt); break;
        default: phase1<12>(lane, tx0, ty0, col2, row2, ctile, xt); break;
    }
    __builtin_amdgcn_sched_barrier(0);         // keep wf loads out of phase-1 live range

    // ---- weights (prepacked bf16 fragments) + demod/bias ----
    bf16x8 wf[9][2];
    #pragma unroll
    for (int tp = 0; tp < 9; ++tp) {
        wf[tp][0] = *(const bf16x8*)(wpack + (size_t)((tp * 4 + kg) * 32 + npx) * 8);
        wf[tp][1] = *(const bf16x8*)(wpack + (size_t)((tp * 4 + kg) * 32 + 16 + npx) * 8);
    }
    float dc[2][4], bs[2][4];
    #pragma unroll
    for (int ob = 0; ob < 2; ++ob)
        #pragma unroll
        for (int rg = 0; rg < 4; ++rg) {
            int oc = ob * 16 + kg * 4 + rg;
            dc[ob][rg] = dcoef[b * CH + oc];
            bs[ob][rg] = cb[oc];
        }
    __syncthreads();

    // ---- phase 2: MFMA conv (4 iterations per wave; group = one 16-px row) ----
    #pragma unroll 1
    for (int it = 0; it < 4; ++it) {
        int py_l = it * 4 + wv;                // 16 rows
        int px_l = npx;
        f32x4 a0 = {0.f, 0.f, 0.f, 0.f};
        f32x4 a1 = {0.f, 0.f, 0.f, 0.f};
        #pragma unroll
        for (int ky = 0; ky < 3; ++ky) {
            int rowb = (py_l + ky) * 18;
            #pragma unroll
            for (int kx = 0; kx < 3; ++kx) {
                int cc = px_l + kx;
                bf16x8 bf = *(const bf16x8*)(xt + (((rowb + cc) << 2) + (kg ^ (cc & 3))) * 4);
                a0 = __builtin_amdgcn_mfma_f32_16x16x32_bf16(wf[ky * 3 + kx][0], bf, a0, 0, 0, 0);
                a1 = __builtin_amdgcn_mfma_f32_16x16x32_bf16(wf[ky * 3 + kx][1], bf, a1, 0, 0, 0);
            }
        }
        int py = ty0 + py_l, px = tx0 + px_l;
        size_t pbase = (size_t)py * 256 + px;
        {
            float y0 = a0[0] * dc[0][0] + bs[0][0];
            float y1 = a0[1] * dc[0][1] + bs[0][1];
            float y2 = a0[2] * dc[0][2] + bs[0][2];
            float y3 = a0[3] * dc[0][3] + bs[0][3];
            y0 = (y0 > 0.f ? y0 : 0.2f * y0) * 1.4142135623730951f;
            y1 = (y1 > 0.f ? y1 : 0.2f * y1) * 1.4142135623730951f;
            y2 = (y2 > 0.f ? y2 : 0.2f * y2) * 1.4142135623730951f;
            y3 = (y3 > 0.f ? y3 : 0.2f * y3) * 1.4142135623730951f;
            int lp0 = kg * 2;
            tokens[((size_t)(b * NL + lp0)) * NPIX + pbase] = packbf(y0, y1);
            tokens[((size_t)(b * NL + lp0 + 1)) * NPIX + pbase] = packbf(y2, y3);
        }
        {
            float y0 = a1[0] * dc[1][0] + bs[1][0];
            float y1 = a1[1] * dc[1][1] + bs[1][1];
            float y2 = a1[2] * dc[1][2] + bs[1][2];
            float y3 = a1[3] * dc[1][3] + bs[1][3];
            y0 = (y0 > 0.f ? y0 : 0.2f * y0) * 1.4142135623730951f;
            y1 = (y1 > 0.f ? y1 : 0.2f * y1) * 1.4142135623730951f;
            y2 = (y2 > 0.f ? y2 : 0.2f * y2) * 1.4142135623730951f;
            y3 = (y3 > 0.f ? y3 : 0.2f * y3) * 1.4142135623730951f;
            int lp0 = 8 + kg * 2;
            tokens[((size_t)(b * NL + lp0)) * NPIX + pbase] = packbf(y0, y1);
            tokens[((size_t)(b * NL + lp0 + 1)) * NPIX + pbase] = packbf(y2, y3);
        }
    }
}

// ---- K3a: recon stage 1, LDS-staged — 1-D grid, b = bid&7 (XCD pin) ----
// U[b][l][i][cx] (fp16x2) = sum_j w(j,cx) * T[i][j]; (jlo,jhi,w) shared by row pair
__global__ __launch_bounds__(256) void k_recon1(const uint32_t* __restrict__ tokens,
                                                const int* __restrict__ ctab,
                                                const float* __restrict__ ftab,
                                                const int* __restrict__ stab,
                                                uint32_t* __restrict__ U, LevelParams p) {
    __shared__ float2 cf[256];                 // (cell as int-bits, frac) per pixel col
    __shared__ int sl[260];                    // lower-bound table S[0..r]
    __shared__ uint32_t tok[8][256];           // 8 token rows (bf16x2)
    int bid = blockIdx.x;                      // 4096
    int b = bid & 7;
    int rest = bid >> 3;                       // 0..511
    int l = rest >> 5;
    int grp = rest & 31;
    int tid = threadIdx.x;
    int lane = tid & 63, wv = tid >> 6;
    int r = p.res[l];

    cf[tid] = make_float2(__int_as_float(ctab[l * 256 + tid]), ftab[l * 256 + tid]);
    for (int q = tid; q <= r; q += 256) sl[q] = stab[p.soff[l] + q];
    int i0 = grp * 8 + wv * 2;                 // first of this wave's 2 rows
    const uint32_t* trow = tokens + (size_t)(b * NL + l) * NPIX + i0 * 256;
    *(uint4*)&tok[wv * 2 + 0][lane * 4] = *(const uint4*)(trow + lane * 4);
    *(uint4*)&tok[wv * 2 + 1][lane * 4] = *(const uint4*)(trow + 256 + lane * 4);
    __syncthreads();

    uint32_t* Ul0 = U + (size_t)b * (p.sumr * 256) + p.uoff[l] + (size_t)i0 * r;
    uint32_t* Ul1 = Ul0 + r;
    int nck = p.nck[l];
    #pragma unroll 1
    for (int ck = 0; ck < nck; ++ck) {
        int cx = ck * 64 + lane;
        bool valid = cx < r;
        int jlo = 0, jhi = -1;
        if (valid) {
            jlo = (cx > 0) ? sl[cx - 1] : 0;
            jhi = sl[min(cx + 1, r)] - 1;
        }
        float a00 = 0.f, a01 = 0.f, a10 = 0.f, a11 = 0.f;
        for (int j = jlo; j <= jhi; ++j) {
            float2 cfv = cf[j];
            int c = __float_as_int(cfv.x);
            float f = cfv.y;
            float w = (c == cx) ? (1.f - f) : f;
            uint32_t tv0 = tok[wv * 2 + 0][j];
            uint32_t tv1 = tok[wv * 2 + 1][j];
            a00 += w * bflo(tv0);
            a01 += w * bfhi(tv0);
            a10 += w * bflo(tv1);
            a11 += w * bfhi(tv1);
        }
        if (valid) {
            Ul0[cx] = packh2(a00, a01);
            Ul1[cx] = packh2(a10, a11);
        }
    }
}

// ---- K3b: recon stage 2 — 1-D grid, b = bid&7 (XCD pin) ----
__global__ __launch_bounds__(256) void k_recon2(const uint32_t* __restrict__ U,
                                                const int* __restrict__ ctab,
                                                const float* __restrict__ ftab,
                                                const int* __restrict__ stab,
                                                float* __restrict__ R, LevelParams p) {
    int bid = blockIdx.x;
    int b = bid & 7;
    int bx = bid >> 3;
    int wid = bx * 4 + (threadIdx.x >> 6);
    int lane = threadIdx.x & 63;
    if (wid >= p.nwaves) return;
    int l = 0;
    #pragma unroll
    for (int q = 1; q < NL; ++q) if (wid >= p.cwoff[q]) l = q;
    int u = wid - p.cwoff[l];
    int r = p.res[l];
    int nck = p.nck[l];
    int cy = u / nck;
    int ck = u - cy * nck;
    int cx = ck * 64 + lane;
    bool valid = cx < r;
    const int* Sl = stab + p.soff[l];
    int ilo = (cy > 0) ? Sl[cy - 1] : 0;
    int ihi = Sl[min(cy + 1, r)] - 1;
    const uint32_t* Ub = U + (size_t)b * (p.sumr * 256) + p.uoff[l];
    const int* crow = ctab + l * 256;
    const float* frow = ftab + l * 256;
    float a0 = 0.f, a1 = 0.f;
    for (int i = ilo; i <= ihi; ++i) {
        int c = crow[i];
        float f = frow[i];
        float w = (c == cy) ? (1.f - f) : f;
        if (valid) {
            uint32_t uu = Ub[(size_t)i * r + cx];
            a0 += w * h2lo(uu);
            a1 += w * h2hi(uu);
        }
    }
    if (!valid) return;
    float* Rbl = R + (size_t)(b * NL + l) * TD * 2;
    if (p.hashed[l]) {
        uint32_t h = ((uint32_t)cx ^ ((uint32_t)cy * PRIME)) & (TD - 1);
        atomicAdd(&Rbl[2 * h], a0);
        atomicAdd(&Rbl[2 * h + 1], a1);
    } else {
        *(float2*)(Rbl + 2 * (cy * r + cx)) = make_float2(a0, a1);
    }
}

// ---- K4: residual + LayerNorm(16384) -> FP32 out; b = bid&7 (XCD pin) ----
__global__ __launch_bounds__(512) void k_ln(const float* __restrict__ R,
                                            const float* __restrict__ inp,
                                            float* __restrict__ out) {
    int bid = blockIdx.x;                       // 128
    int row = (bid & 7) * NL + (bid >> 3);      // b*NL + l
    const float4* rv = (const float4*)(R + (size_t)row * 16384);
    const float4* iv = (const float4*)(inp + (size_t)row * 16384);
    int tid = threadIdx.x;
    float sum = 0.f, ssq = 0.f;
    for (int k = tid; k < 4096; k += 512) {
        float4 a = rv[k], c = iv[k];
        float x0 = a.x + c.x, x1 = a.y + c.y, x2 = a.z + c.z, x3 = a.w + c.w;
        sum += x0 + x1 + x2 + x3;
        ssq += x0 * x0 + x1 * x1 + x2 * x2 + x3 * x3;
    }
    #pragma unroll
    for (int off = 32; off > 0; off >>= 1) {
        sum += __shfl_xor(sum, off, 64);
        ssq += __shfl_xor(ssq, off, 64);
    }
    __shared__ float red[16];
    int w = tid >> 6;
    if ((tid & 63) == 0) { red[w * 2] = sum; red[w * 2 + 1] = ssq; }
    __syncthreads();
    sum = 0.f; ssq = 0.f;
    #pragma unroll
    for (int q = 0; q < 8; ++q) { sum += red[q * 2]; ssq += red[q * 2 + 1]; }
    float mu = sum * (1.f / 16384.f);
    float var = ssq * (1.f / 16384.f) - mu * mu;
    float inv = rsqrtf(var + 1e-5f);
    float4* ob = (float4*)(out + (size_t)row * 16384);
    for (int k = tid; k < 4096; k += 512) {
        float4 a = rv[k], c = iv[k];
        float4 o4;
        o4.x = (a.x + c.x - mu) * inv;
        o4.y = (a.y + c.y - mu) * inv;
        o4.z = (a.z + c.z - mu) * inv;
        o4.w = (a.w + c.w - mu) * inv;
        ob[k] = o4;
    }
}

extern "C" void kernel_launch(void* const* d_in, const int* in_sizes, int n_in,
                              void* d_out, int out_size, void* d_ws, size_t ws_size,
                              hipStream_t stream) {
    const float* inputs = (const float*)d_in[0];
    const float* s      = (const float*)d_in[1];
    const float* coords = (const float*)d_in[2];
    const float* aw     = (const float*)d_in[3];
    const float* ab     = (const float*)d_in[4];
    const float* cw     = (const float*)d_in[5];
    const float* cb     = (const float*)d_in[6];

    char* ws = (char*)d_ws;
    uint32_t* U      = (uint32_t*)(ws);                 // 11.7 MB used (fp16x2 packed)
    uint32_t* ctileG = (uint32_t*)(ws + 16777216);      // 14.5 MB (dead part of U slot)
    uint32_t* tokens = (uint32_t*)(ws + 33554432);      // 33,554,432 B
    float*    R      = (float*)(ws + 67108864);         //  8,388,608 B
    float*    styles = (float*)(ws + 75497472);         // 1 KB
    float*    dcoef  = (float*)(ws + 75498496);         // 1 KB
    int*      ctab   = (int*)(ws + 75499520);           // 16 KB
    float*    ftab   = (float*)(ws + 75515904);         // 16 KB
    int*      stab   = (int*)(ws + 75532288);           // 8 KB
    unsigned short* wpack = (unsigned short*)(ws + 75540480); // 18.4 KB

    // RES_LIST exactly as numpy computes it (double libm ops).
    LevelParams p;
    double bb = exp((log(256.0) - log(16.0)) / 15.0);
    int uoff = 0, soff = 0, cwoff = 0, sumr = 0;
    for (int l = 0; l < NL; ++l) {
        int r = (int)floor(16.0 * pow(bb, (double)l));
        p.res[l] = r;
        p.hashed[l] = (r * r > TD) ? 1 : 0;
        p.uoff[l] = uoff;
        p.soff[l] = soff;
        p.cwoff[l] = cwoff;
        int nck = (r + 63) >> 6;
        p.nck[l] = nck;
        uoff += r * 256;
        soff += r + 2;
        cwoff += r * nck;
        sumr += r;
    }
    p.sumr = sumr;
    p.nwaves = cwoff;

    hipLaunchKernelGGL(k_prep, dim3(NB + NL + 36 + 512), dim3(256), 0, stream,
                       s, aw, ab, cw, coords, styles, dcoef, ctab, ftab, stab, wpack, R, p);
    hipLaunchKernelGGL(k_gather, dim3(2048), dim3(256), 0, stream,
                       inputs, ctab, styles, ctileG, p);
    hipLaunchKernelGGL(k_conv, dim3(2048), dim3(256), 0, stream,
                       ctileG, ctab, ftab, wpack, cb, dcoef, tokens, p);
    hipLaunchKernelGGL(k_recon1, dim3(NL * 32 * NB), dim3(256), 0, stream,
                       tokens, ctab, ftab, stab, U, p);
    hipLaunchKernelGGL(k_recon2, dim3(((p.nwaves + 3) / 4) * NB), dim3(256), 0, stream,
                       U, ctab, ftab, stab, R, p);
    hipLaunchKernelGGL(k_ln, dim3(NB * NL), dim3(512), 0, stream,
                       R, inputs, (float*)d_out);
}

// Round 22
// 98.591 us; speedup vs baseline: 1.6518x; 1.0007x over previous
//
#include <hip/hip_runtime.h>
#include <hip/hip_fp16.h>
#include <cmath>
#include <cstdint>

#define NB 8
#define NL 16
#define TD 8192
#define NPIX 65536
#define CH 32
#define SD 512

static constexpr uint32_t PRIME = 2654435761u;

typedef __attribute__((ext_vector_type(8))) _Float16 f16x8;
typedef __attribute__((ext_vector_type(4))) float f32x4;

// per-level corner-tile capacities for a 16x16 tile (+halo, 17-px span)
static constexpr int cNCX[16] = {4,5,5,5,6,6,7,7,8,9,10,12,13,15,18,20};
static constexpr int CTOFF[17] = {0,16,41,66,91,127,163,212,261,325,406,506,650,819,1044,1368,1768};

struct LevelParams {
    int res[NL];
    int hashed[NL];
    int uoff[NL];    // prefix of 256*r u32 (per batch) into packed U [i][cx]
    int soff[NL];    // prefix of (r+2) ints into stab
    int cwoff[NL];   // recon2 wave prefix (r*nck)
    int nck[NL];     // ceil(r/64)
    int sumr;
    int nwaves;      // recon2 waves per batch
};

// ---- bf16 helpers (RNE) ----
__device__ __forceinline__ unsigned short f2bf(float f) {
    uint32_t u = __float_as_uint(f);
    return (unsigned short)((u + 0x7fffu + ((u >> 16) & 1u)) >> 16);
}
__device__ __forceinline__ float bflo(uint32_t u) { return __uint_as_float(u << 16); }
__device__ __forceinline__ float bfhi(uint32_t u) { return __uint_as_float(u & 0xffff0000u); }
__device__ __forceinline__ uint32_t packbf(float a, float b) {
    return (uint32_t)f2bf(a) | ((uint32_t)f2bf(b) << 16);
}
// ---- fp16x2 pack helpers ----
__device__ __forceinline__ uint32_t packh2(float a, float b) {
    return (uint32_t)__half_as_ushort(__float2half_rn(a)) |
           ((uint32_t)__half_as_ushort(__float2half_rn(b)) << 16);
}
__device__ __forceinline__ float h2lo(uint32_t u) {
    return __half2float(__ushort_as_half((unsigned short)(u & 0xffffu)));
}
__device__ __forceinline__ float h2hi(uint32_t u) {
    return __half2float(__ushort_as_half((unsigned short)(u >> 16)));
}
__device__ __forceinline__ __half2 u2h2(uint32_t u) {
    union { uint32_t u; __half2 h; } v; v.u = u; return v.h;
}
__device__ __forceinline__ uint32_t h22u(__half2 h) {
    union { __half2 h; uint32_t u; } v; v.h = h; return v.u;
}

// ---- K_prep: styles+dcoef (0..7), wtab (8..23), wpack (24..59), R-zero (60..571) ----
__global__ __launch_bounds__(256) void k_prep(
    const float* __restrict__ s, const float* __restrict__ aw,
    const float* __restrict__ ab, const float* __restrict__ cw,
    const float* __restrict__ coords,
    float* __restrict__ styles, float* __restrict__ dcoef,
    int* __restrict__ ctab, float* __restrict__ ftab, int* __restrict__ stab,
    unsigned short* __restrict__ wpack, float* __restrict__ R, LevelParams p) {
    int bb = blockIdx.x;
    int t = threadIdx.x;
    if (bb < NB) {
        int b = bb;
        int c = t >> 3, part = t & 7;               // 32 ch x 8 parts
        const float* sv = s + b * SD + part * 64;
        const float* wv = aw + c * SD + part * 64;
        float acc = 0.f;
        #pragma unroll 8
        for (int k = 0; k < 64; ++k) acc += sv[k] * wv[k];
        acc += __shfl_xor(acc, 1, 64);
        acc += __shfl_xor(acc, 2, 64);
        acc += __shfl_xor(acc, 4, 64);
        __shared__ float st_sh[CH];
        if (part == 0) {
            float st = acc * 0.04419417382415922f /* 1/sqrt(512) */ + ab[c];
            styles[b * CH + c] = st;
            st_sh[c] = st;
        }
        __syncthreads();
        if (t < CH) {
            float d = 0.f;
            for (int i = 0; i < CH; ++i) {
                const float* w9 = cw + (t * CH + i) * 9;
                float ws = 0.f;
                #pragma unroll
                for (int k = 0; k < 9; ++k) ws += w9[k] * w9[k];
                float si = st_sh[i];
                d += ws * si * si;
            }
            dcoef[b * CH + t] = rsqrtf(d + 1e-8f);
        }
    } else if (bb < NB + NL) {
        int l = bb - NB;
        int j = t;
        int r = p.res[l];
        float g = coords[2 * j];                   // x-coord of col j == y-coord of row j
        float px = g * (float)(r - 1);
        float fl = floorf(px);
        float f = px - fl;
        int c = min((int)fl, r - 2);
        ctab[l * 256 + j] = c;
        ftab[l * 256 + j] = f;
        __shared__ int cs[256];
        cs[j] = c;
        __syncthreads();
        for (int cc = j; cc <= r; cc += 256) {
            int cnt = 0;
            for (int i = 0; i < 256; ++i) cnt += (cs[i] < cc) ? 1 : 0;
            stab[p.soff[l] + cc] = cnt;
        }
    } else if (bb < NB + NL + 36) {
        int idx = (bb - NB - NL) * 256 + t;
        if (idx < 9 * 4 * 32 * 8) {
            int j = idx & 7;
            int o = (idx >> 3) & 31;
            int kgi = (idx >> 8) & 3;
            int tap = idx >> 10;
            wpack[idx] = __half_as_ushort(__float2half_rn(cw[(o * 32 + kgi * 8 + j) * 9 + tap]));
        }
    } else {
        // zero-fill R: blocks 60..571, each 1024 uint4 (16 KB)
        float4* Rv = (float4*)R;
        int base = (bb - NB - NL - 36) * 1024;
        float4 z = make_float4(0.f, 0.f, 0.f, 0.f);
        #pragma unroll
        for (int q = 0; q < 4; ++q)
            Rv[base + q * 256 + t] = z;
    }
}

// ---- K_gather: pre-gather deduped premod corner tiles (fp16x2) per (tile,batch) ----
__global__ __launch_bounds__(256) void k_gather(
    const float* __restrict__ tables, const int* __restrict__ ctab,
    const float* __restrict__ styles, uint32_t* __restrict__ ctileG,
    LevelParams p) {
    __shared__ int cxbase[NL], cybase[NL], ncxA[NL], ncyA[NL];
    int bid = blockIdx.x;                      // 2048
    int b = bid & 7;
    int t = bid >> 3;
    int tx0 = (t & 15) * 16, ty0 = (t >> 4) * 16;
    int tid = threadIdx.x;
    const float* tb = tables + (size_t)b * NL * TD * 2;
    if (tid < NL) {
        int l = tid;
        int cxb = ctab[l * 256 + max(tx0 - 1, 0)];
        int cyb = ctab[l * 256 + max(ty0 - 1, 0)];
        cxbase[l] = cxb;
        cybase[l] = cyb;
        ncxA[l] = ctab[l * 256 + min(tx0 + 16, 255)] - cxb + 2;
        ncyA[l] = ctab[l * 256 + min(ty0 + 16, 255)] - cyb + 2;
    }
    __syncthreads();
    uint32_t* out = ctileG + (size_t)bid * 1768;
    #pragma unroll
    for (int l = 0; l < NL; ++l) {
        const int NCXl = cNCX[l];
        const int CAP = (CTOFF[l + 1] - CTOFF[l]);
        float s0 = styles[b * CH + 2 * l], s1 = styles[b * CH + 2 * l + 1];
        for (int u2 = tid; u2 < CAP; u2 += 256) {
            int sy = u2 / NCXl;
            int sx = u2 - sy * NCXl;
            uint32_t val = 0u;
            if (sx < ncxA[l] && sy < ncyA[l]) {
                int ax = cxbase[l] + sx, ay = cybase[l] + sy;
                int r = p.res[l];
                uint32_t idx = p.hashed[l]
                    ? (((uint32_t)ax ^ ((uint32_t)ay * PRIME)) & (TD - 1))
                    : (uint32_t)(ay * r + ax);
                float2 g = *(const float2*)(tb + (size_t)l * TD * 2 + 2 * idx);
                val = packh2(g.x * s0, g.y * s1);
            }
            out[CTOFF[l] + u2] = val;          // coalesced
        }
    }
}

// ---- fused retrieve feature: packed-fp16 bilinear (both channels per op) ----
// cp/rp = {rel_cell, h2(1-f) bits, h2(f) bits, unused}
template<int L>
__device__ __forceinline__ uint32_t feat1p(const uint4& cp, const uint4& rp,
                                           const uint32_t* ctile) {
    int a = CTOFF[L] + (int)rp.x * cNCX[L] + (int)cp.x;
    __half2 c00 = u2h2(ctile[a]), c10 = u2h2(ctile[a + 1]);
    __half2 c01 = u2h2(ctile[a + cNCX[L]]), c11 = u2h2(ctile[a + cNCX[L] + 1]);
    __half2 wxA = u2h2(cp.y), wxB = u2h2(cp.z);
    __half2 t0 = __hfma2(wxB, c10, __hmul2(wxA, c00));
    __half2 t1 = __hfma2(wxB, c11, __hmul2(wxA, c01));
    __half2 f = __hfma2(u2h2(rp.z), t1, __hmul2(u2h2(rp.y), t0));
    return h22u(f);
}

// ---- phase 1: one wave = 4 levels, all 324 halo px ----
template<int L0>
__device__ __forceinline__ void phase1(int lane, int tx0, int ty0,
                                       const uint4* colP, const uint4* rowP,
                                       const uint32_t* ctile, uint32_t* xt) {
    constexpr int q = L0 / 4;
    #pragma unroll
    for (int it = 0; it < 6; ++it) {
        int pl = it * 64 + lane;
        int rr = pl / 18, cc = pl - rr * 18;
        int gy = ty0 + rr - 1, gx = tx0 + cc - 1;
        uint4 v = make_uint4(0u, 0u, 0u, 0u);
        if (pl < 324 && (unsigned)gy < 256u && (unsigned)gx < 256u) {
            uint4 cp0 = colP[(L0 + 0) * 18 + cc], rp0 = rowP[(L0 + 0) * 18 + rr];
            uint4 cp1 = colP[(L0 + 1) * 18 + cc], rp1 = rowP[(L0 + 1) * 18 + rr];
            uint4 cp2 = colP[(L0 + 2) * 18 + cc], rp2 = rowP[(L0 + 2) * 18 + rr];
            uint4 cp3 = colP[(L0 + 3) * 18 + cc], rp3 = rowP[(L0 + 3) * 18 + rr];
            v.x = feat1p<L0 + 0>(cp0, rp0, ctile);
            v.y = feat1p<L0 + 1>(cp1, rp1, ctile);
            v.z = feat1p<L0 + 2>(cp2, rp2, ctile);
            v.w = feat1p<L0 + 3>(cp3, rp3, ctile);
        }
        if (pl < 324)
            *(uint4*)(xt + (size_t)(pl * 4 + (q ^ (cc & 3))) * 4) = v;
    }
}

// ---- K2: FUSED retrieve+mod+MFMA 3x3 conv (fp16 features); corners pre-gathered ----
__global__ __launch_bounds__(256) void k_conv(
    const uint32_t* __restrict__ ctileG, const int* __restrict__ ctab,
    const float* __restrict__ ftab,
    const unsigned short* __restrict__ wpack, const float* __restrict__ cb,
    const float* __restrict__ dcoef, uint32_t* __restrict__ tokens,
    LevelParams p) {
    __shared__ uint32_t xt[18 * 18 * 16];      // 20736 B feature tile (fp16x2 chunks)
    __shared__ uint32_t ctile[1768];           // 7072 B premod corners (fp16x2)
    __shared__ uint4 colP[NL * 18];            // 4608 B {rel, h2(1-fx), h2(fx)}
    __shared__ uint4 rowP[NL * 18];            // 4608 B {rel, h2(1-fy), h2(fy)}
    __shared__ int cxbase[NL], cybase[NL];

    int bid = blockIdx.x;
    int b = bid & 7;
    int t = bid >> 3;
    int tx0 = (t & 15) * 16, ty0 = (t >> 4) * 16;
    int tid = threadIdx.x;
    int lane = tid & 63, wv = tid >> 6;        // 4 waves
    int npx = lane & 15, kg = lane >> 4;

    // ---- setup: extents + coalesced ctile load + colP/rowP ----
    if (tid < NL) {
        int l = tid;
        cxbase[l] = ctab[l * 256 + max(tx0 - 1, 0)];
        cybase[l] = ctab[l * 256 + max(ty0 - 1, 0)];
    }
    {
        const uint4* src = (const uint4*)(ctileG + (size_t)bid * 1768);
        for (int i = tid; i < 442; i += 256)
            *(uint4*)(ctile + i * 4) = src[i];
    }
    __syncthreads();
    for (int u0 = tid; u0 < NL * 36; u0 += 256) {
        int l = u0 / 36, pos = u0 - l * 36;
        if (pos < 18) {
            int gx = tx0 - 1 + pos;
            int gxc = min(max(gx, 0), 255);
            float f = ftab[l * 256 + gxc];
            colP[l * 18 + pos] = make_uint4(
                (uint32_t)(ctab[l * 256 + gxc] - cxbase[l]),
                h22u(__float2half2_rn(1.f - f)), h22u(__float2half2_rn(f)), 0u);
        } else {
            int pr = pos - 18;
            int gy = ty0 - 1 + pr;
            int gyc = min(max(gy, 0), 255);
            float f = ftab[l * 256 + gyc];
            rowP[l * 18 + pr] = make_uint4(
                (uint32_t)(ctab[l * 256 + gyc] - cybase[l]),
                h22u(__float2half2_rn(1.f - f)), h22u(__float2half2_rn(f)), 0u);
        }
    }
    __syncthreads();

    // ---- phase 1: wave-uniform 4-level feature computation -> xt (all-LDS) ----
    switch (wv) {
        case 0: phase1<0>(lane, tx0, ty0, colP, rowP, ctile, xt); break;
        case 1: phase1<4>(lane, tx0, ty0, colP, rowP, ctile, xt); break;
        case 2: phase1<8>(lane, tx0, ty0, colP, rowP, ctile, xt); break;
        default: phase1<12>(lane, tx0, ty0, colP, rowP, ctile, xt); break;
    }
    __builtin_amdgcn_sched_barrier(0);         // keep wf loads out of phase-1 live range

    // ---- weights (prepacked fp16 fragments) + demod/bias ----
    f16x8 wf[9][2];
    #pragma unroll
    for (int tp = 0; tp < 9; ++tp) {
        wf[tp][0] = *(const f16x8*)(wpack + (size_t)((tp * 4 + kg) * 32 + npx) * 8);
        wf[tp][1] = *(const f16x8*)(wpack + (size_t)((tp * 4 + kg) * 32 + 16 + npx) * 8);
    }
    float dc[2][4], bs[2][4];
    #pragma unroll
    for (int ob = 0; ob < 2; ++ob)
        #pragma unroll
        for (int rg = 0; rg < 4; ++rg) {
            int oc = ob * 16 + kg * 4 + rg;
            dc[ob][rg] = dcoef[b * CH + oc];
            bs[ob][rg] = cb[oc];
        }
    __syncthreads();

    // ---- phase 2: f16 MFMA conv (4 iterations per wave; group = one 16-px row) ----
    #pragma unroll 1
    for (int it = 0; it < 4; ++it) {
        int py_l = it * 4 + wv;                // 16 rows
        int px_l = npx;
        f32x4 a0 = {0.f, 0.f, 0.f, 0.f};
        f32x4 a1 = {0.f, 0.f, 0.f, 0.f};
        #pragma unroll
        for (int ky = 0; ky < 3; ++ky) {
            int rowb = (py_l + ky) * 18;
            #pragma unroll
            for (int kx = 0; kx < 3; ++kx) {
                int cc = px_l + kx;
                f16x8 bf = *(const f16x8*)(xt + (((rowb + cc) << 2) + (kg ^ (cc & 3))) * 4);
                a0 = __builtin_amdgcn_mfma_f32_16x16x32_f16(wf[ky * 3 + kx][0], bf, a0, 0, 0, 0);
                a1 = __builtin_amdgcn_mfma_f32_16x16x32_f16(wf[ky * 3 + kx][1], bf, a1, 0, 0, 0);
            }
        }
        int py = ty0 + py_l, px = tx0 + px_l;
        size_t pbase = (size_t)py * 256 + px;
        {
            float y0 = a0[0] * dc[0][0] + bs[0][0];
            float y1 = a0[1] * dc[0][1] + bs[0][1];
            float y2 = a0[2] * dc[0][2] + bs[0][2];
            float y3 = a0[3] * dc[0][3] + bs[0][3];
            y0 = (y0 > 0.f ? y0 : 0.2f * y0) * 1.4142135623730951f;
            y1 = (y1 > 0.f ? y1 : 0.2f * y1) * 1.4142135623730951f;
            y2 = (y2 > 0.f ? y2 : 0.2f * y2) * 1.4142135623730951f;
            y3 = (y3 > 0.f ? y3 : 0.2f * y3) * 1.4142135623730951f;
            int lp0 = kg * 2;
            tokens[((size_t)(b * NL + lp0)) * NPIX + pbase] = packbf(y0, y1);
            tokens[((size_t)(b * NL + lp0 + 1)) * NPIX + pbase] = packbf(y2, y3);
        }
        {
            float y0 = a1[0] * dc[1][0] + bs[1][0];
            float y1 = a1[1] * dc[1][1] + bs[1][1];
            float y2 = a1[2] * dc[1][2] + bs[1][2];
            float y3 = a1[3] * dc[1][3] + bs[1][3];
            y0 = (y0 > 0.f ? y0 : 0.2f * y0) * 1.4142135623730951f;
            y1 = (y1 > 0.f ? y1 : 0.2f * y1) * 1.4142135623730951f;
            y2 = (y2 > 0.f ? y2 : 0.2f * y2) * 1.4142135623730951f;
            y3 = (y3 > 0.f ? y3 : 0.2f * y3) * 1.4142135623730951f;
            int lp0 = 8 + kg * 2;
            tokens[((size_t)(b * NL + lp0)) * NPIX + pbase] = packbf(y0, y1);
            tokens[((size_t)(b * NL + lp0 + 1)) * NPIX + pbase] = packbf(y2, y3);
        }
    }
}

// ---- K3a: recon stage 1, LDS-staged — 1-D grid, b = bid&7 (XCD pin) ----
// U[b][l][i][cx] (fp16x2) = sum_j w(j,cx) * T[i][j]; (jlo,jhi,w) shared by row pair
__global__ __launch_bounds__(256) void k_recon1(const uint32_t* __restrict__ tokens,
                                                const int* __restrict__ ctab,
                                                const float* __restrict__ ftab,
                                                const int* __restrict__ stab,
                                                uint32_t* __restrict__ U, LevelParams p) {
    __shared__ float2 cf[256];                 // (cell as int-bits, frac) per pixel col
    __shared__ int sl[260];                    // lower-bound table S[0..r]
    __shared__ uint32_t tok[8][256];           // 8 token rows (bf16x2)
    int bid = blockIdx.x;                      // 4096
    int b = bid & 7;
    int rest = bid >> 3;                       // 0..511
    int l = rest >> 5;
    int grp = rest & 31;
    int tid = threadIdx.x;
    int lane = tid & 63, wv = tid >> 6;
    int r = p.res[l];

    cf[tid] = make_float2(__int_as_float(ctab[l * 256 + tid]), ftab[l * 256 + tid]);
    for (int q = tid; q <= r; q += 256) sl[q] = stab[p.soff[l] + q];
    int i0 = grp * 8 + wv * 2;                 // first of this wave's 2 rows
    const uint32_t* trow = tokens + (size_t)(b * NL + l) * NPIX + i0 * 256;
    *(uint4*)&tok[wv * 2 + 0][lane * 4] = *(const uint4*)(trow + lane * 4);
    *(uint4*)&tok[wv * 2 + 1][lane * 4] = *(const uint4*)(trow + 256 + lane * 4);
    __syncthreads();

    uint32_t* Ul0 = U + (size_t)b * (p.sumr * 256) + p.uoff[l] + (size_t)i0 * r;
    uint32_t* Ul1 = Ul0 + r;
    int nck = p.nck[l];
    #pragma unroll 1
    for (int ck = 0; ck < nck; ++ck) {
        int cx = ck * 64 + lane;
        bool valid = cx < r;
        int jlo = 0, jhi = -1;
        if (valid) {
            jlo = (cx > 0) ? sl[cx - 1] : 0;
            jhi = sl[min(cx + 1, r)] - 1;
        }
        float a00 = 0.f, a01 = 0.f, a10 = 0.f, a11 = 0.f;
        for (int j = jlo; j <= jhi; ++j) {
            float2 cfv = cf[j];
            int c = __float_as_int(cfv.x);
            float f = cfv.y;
            float w = (c == cx) ? (1.f - f) : f;
            uint32_t tv0 = tok[wv * 2 + 0][j];
            uint32_t tv1 = tok[wv * 2 + 1][j];
            a00 += w * bflo(tv0);
            a01 += w * bfhi(tv0);
            a10 += w * bflo(tv1);
            a11 += w * bfhi(tv1);
        }
        if (valid) {
            Ul0[cx] = packh2(a00, a01);
            Ul1[cx] = packh2(a10, a11);
        }
    }
}

// ---- K3b: recon stage 2 — 1-D grid, b = bid&7 (XCD pin) ----
__global__ __launch_bounds__(256) void k_recon2(const uint32_t* __restrict__ U,
                                                const int* __restrict__ ctab,
                                                const float* __restrict__ ftab,
                                                const int* __restrict__ stab,
                                                float* __restrict__ R, LevelParams p) {
    int bid = blockIdx.x;
    int b = bid & 7;
    int bx = bid >> 3;
    int wid = bx * 4 + (threadIdx.x >> 6);
    int lane = threadIdx.x & 63;
    if (wid >= p.nwaves) return;
    int l = 0;
    #pragma unroll
    for (int q = 1; q < NL; ++q) if (wid >= p.cwoff[q]) l = q;
    int u = wid - p.cwoff[l];
    int r = p.res[l];
    int nck = p.nck[l];
    int cy = u / nck;
    int ck = u - cy * nck;
    int cx = ck * 64 + lane;
    bool valid = cx < r;
    const int* Sl = stab + p.soff[l];
    int ilo = (cy > 0) ? Sl[cy - 1] : 0;
    int ihi = Sl[min(cy + 1, r)] - 1;
    const uint32_t* Ub = U + (size_t)b * (p.sumr * 256) + p.uoff[l];
    const int* crow = ctab + l * 256;
    const float* frow = ftab + l * 256;
    float a0 = 0.f, a1 = 0.f;
    for (int i = ilo; i <= ihi; ++i) {
        int c = crow[i];
        float f = frow[i];
        float w = (c == cy) ? (1.f - f) : f;
        if (valid) {
            uint32_t uu = Ub[(size_t)i * r + cx];
            a0 += w * h2lo(uu);
            a1 += w * h2hi(uu);
        }
    }
    if (!valid) return;
    float* Rbl = R + (size_t)(b * NL + l) * TD * 2;
    if (p.hashed[l]) {
        uint32_t h = ((uint32_t)cx ^ ((uint32_t)cy * PRIME)) & (TD - 1);
        atomicAdd(&Rbl[2 * h], a0);
        atomicAdd(&Rbl[2 * h + 1], a1);
    } else {
        *(float2*)(Rbl + 2 * (cy * r + cx)) = make_float2(a0, a1);
    }
}

// ---- K4: residual + LayerNorm(16384) -> FP32 out; b = bid&7 (XCD pin) ----
__global__ __launch_bounds__(512) void k_ln(const float* __restrict__ R,
                                            const float* __restrict__ inp,
                                            float* __restrict__ out) {
    int bid = blockIdx.x;                       // 128
    int row = (bid & 7) * NL + (bid >> 3);      // b*NL + l
    const float4* rv = (const float4*)(R + (size_t)row * 16384);
    const float4* iv = (const float4*)(inp + (size_t)row * 16384);
    int tid = threadIdx.x;
    float sum = 0.f, ssq = 0.f;
    for (int k = tid; k < 4096; k += 512) {
        float4 a = rv[k], c = iv[k];
        float x0 = a.x + c.x, x1 = a.y + c.y, x2 = a.z + c.z, x3 = a.w + c.w;
        sum += x0 + x1 + x2 + x3;
        ssq += x0 * x0 + x1 * x1 + x2 * x2 + x3 * x3;
    }
    #pragma unroll
    for (int off = 32; off > 0; off >>= 1) {
        sum += __shfl_xor(sum, off, 64);
        ssq += __shfl_xor(ssq, off, 64);
    }
    __shared__ float red[16];
    int w = tid >> 6;
    if ((tid & 63) == 0) { red[w * 2] = sum; red[w * 2 + 1] = ssq; }
    __syncthreads();
    sum = 0.f; ssq = 0.f;
    #pragma unroll
    for (int q = 0; q < 8; ++q) { sum += red[q * 2]; ssq += red[q * 2 + 1]; }
    float mu = sum * (1.f / 16384.f);
    float var = ssq * (1.f / 16384.f) - mu * mu;
    float inv = rsqrtf(var + 1e-5f);
    float4* ob = (float4*)(out + (size_t)row * 16384);
    for (int k = tid; k < 4096; k += 512) {
        float4 a = rv[k], c = iv[k];
        float4 o4;
        o4.x = (a.x + c.x - mu) * inv;
        o4.y = (a.y + c.y - mu) * inv;
        o4.z = (a.z + c.z - mu) * inv;
        o4.w = (a.w + c.w - mu) * inv;
        ob[k] = o4;
    }
}

extern "C" void kernel_launch(void* const* d_in, const int* in_sizes, int n_in,
                              void* d_out, int out_size, void* d_ws, size_t ws_size,
                              hipStream_t stream) {
    const float* inputs = (const float*)d_in[0];
    const float* s      = (const float*)d_in[1];
    const float* coords = (const float*)d_in[2];
    const float* aw     = (const float*)d_in[3];
    const float* ab     = (const float*)d_in[4];
    const float* cw     = (const float*)d_in[5];
    const float* cb     = (const float*)d_in[6];

    char* ws = (char*)d_ws;
    uint32_t* U      = (uint32_t*)(ws);                 // 11.7 MB used (fp16x2 packed)
    uint32_t* ctileG = (uint32_t*)(ws + 16777216);      // 14.5 MB (dead part of U slot)
    uint32_t* tokens = (uint32_t*)(ws + 33554432);      // 33,554,432 B
    float*    R      = (float*)(ws + 67108864);         //  8,388,608 B
    float*    styles = (float*)(ws + 75497472);         // 1 KB
    float*    dcoef  = (float*)(ws + 75498496);         // 1 KB
    int*      ctab   = (int*)(ws + 75499520);           // 16 KB
    float*    ftab   = (float*)(ws + 75515904);         // 16 KB
    int*      stab   = (int*)(ws + 75532288);           // 8 KB
    unsigned short* wpack = (unsigned short*)(ws + 75540480); // 18.4 KB

    // RES_LIST exactly as numpy computes it (double libm ops).
    LevelParams p;
    double bb = exp((log(256.0) - log(16.0)) / 15.0);
    int uoff = 0, soff = 0, cwoff = 0, sumr = 0;
    for (int l = 0; l < NL; ++l) {
        int r = (int)floor(16.0 * pow(bb, (double)l));
        p.res[l] = r;
        p.hashed[l] = (r * r > TD) ? 1 : 0;
        p.uoff[l] = uoff;
        p.soff[l] = soff;
        p.cwoff[l] = cwoff;
        int nck = (r + 63) >> 6;
        p.nck[l] = nck;
        uoff += r * 256;
        soff += r + 2;
        cwoff += r * nck;
        sumr += r;
    }
    p.sumr = sumr;
    p.nwaves = cwoff;

    hipLaunchKernelGGL(k_prep, dim3(NB + NL + 36 + 512), dim3(256), 0, stream,
                       s, aw, ab, cw, coords, styles, dcoef, ctab, ftab, stab, wpack, R, p);
    hipLaunchKernelGGL(k_gather, dim3(2048), dim3(256), 0, stream,
                       inputs, ctab, styles, ctileG, p);
    hipLaunchKernelGGL(k_conv, dim3(2048), dim3(256), 0, stream,
                       ctileG, ctab, ftab, wpack, cb, dcoef, tokens, p);
    hipLaunchKernelGGL(k_recon1, dim3(NL * 32 * NB), dim3(256), 0, stream,
                       tokens, ctab, ftab, stab, U, p);
    hipLaunchKernelGGL(k_recon2, dim3(((p.nwaves + 3) / 4) * NB), dim3(256), 0, stream,
                       U, ctab, ftab, stab, R, p);
    hipLaunchKernelGGL(k_ln, dim3(NB * NL), dim3(512), 0, stream,
                       R, inputs, (float*)d_out);
}